// Round 8
// baseline (473.982 us; speedup 1.0000x reference)
//
#include <hip/hip_runtime.h>

// ---------- bf16 helpers (bit-level, RNE) ----------
__device__ __forceinline__ float bflo(unsigned int u){ return __builtin_bit_cast(float, (unsigned int)(u<<16)); }
__device__ __forceinline__ float bfhi(unsigned int u){ return __builtin_bit_cast(float, (unsigned int)(u & 0xffff0000u)); }
__device__ __forceinline__ float b2f(unsigned short s){ return __builtin_bit_cast(float, ((unsigned int)s)<<16); }
__device__ __forceinline__ unsigned short f2b(float f){
  unsigned int x = __builtin_bit_cast(unsigned int, f);
  x += 0x7fffu + ((x>>16)&1u);
  return (unsigned short)(x>>16);
}
__device__ __forceinline__ unsigned int packbf(float a, float b){
  return (unsigned int)f2b(a) | ((unsigned int)f2b(b)<<16);
}
__device__ __forceinline__ unsigned short f2h(float f){
  return __builtin_bit_cast(unsigned short, (_Float16)f);
}
__device__ __forceinline__ float dpp_swap1(float s){
  int so = __builtin_amdgcn_mov_dpp(__builtin_bit_cast(int, s), 0xB1, 0xF, 0xF, true); // quad_perm [1,0,3,2]
  return __builtin_bit_cast(float, so);
}

using bf16x8 = __attribute__((ext_vector_type(8))) short;
using f32x4  = __attribute__((ext_vector_type(4))) float;
using f32x2  = __attribute__((ext_vector_type(2))) float;
using h2     = __attribute__((ext_vector_type(2))) _Float16;

__device__ __forceinline__ h2 uh(unsigned int u){ return __builtin_bit_cast(h2, u); }

#define NPOS 65536          // T*H*W
#define SLOT_ELEMS 8388608  // NPOS*128 bf16 elements
#define WM_OFF 6291456      // wm offset (shorts) inside Cs slot (v-fp8 uses first 4194304)

// ---------- K0: conv weights fp32 (O,C,3,3) -> bf16 (tap,O,C);
// projection mats Wq(+scale),Wk,Wv,Wo fp32 -> bf16 [mat][o][c] ----
__global__ __launch_bounds__(256) void k_wprep(const float* __restrict__ w1,
                                               const float* __restrict__ w2,
                                               const float* __restrict__ Wq,
                                               const float* __restrict__ Wk,
                                               const float* __restrict__ Wv,
                                               const float* __restrict__ Wo,
                                               unsigned short* __restrict__ o1,
                                               unsigned short* __restrict__ o2,
                                               unsigned short* __restrict__ wm){
  int idx = blockIdx.x*256 + threadIdx.x;
  if (idx < 147456){
    int o = idx / 1152;
    int rem = idx - o*1152;
    int c = rem / 9;
    int tap = rem - c*9;
    int dsti = tap*16384 + o*128 + c;
    o1[dsti] = f2b(w1[idx]);
    o2[dsti] = f2b(w2[idx]);
  } else if (idx < 212992){
    int idx2 = idx - 147456;
    int mat = idx2 >> 14;
    int ij  = idx2 & 16383;
    // q scale = (1/sqrt(32)) * log2(e) folded into Wq
    float v = (mat==0) ? Wq[ij]*0.2550348613f
            : (mat==1) ? Wk[ij]
            : (mat==2) ? Wv[ij] : Wo[ij];
    wm[idx2] = f2b(v);
  }
}

// ---------- K1: LayerNorm over C, fp32 NCHW input -> (N,C) bf16 ----------
__global__ __launch_bounds__(256) void k_ln_nchw(const float* __restrict__ vid,
                                                 const float* __restrict__ g,
                                                 const float* __restrict__ b,
                                                 unsigned short* __restrict__ xf){
  int n = blockIdx.x*256 + threadIdx.x;
  int t = n >> 14, hw = n & 16383;
  const float* base = vid + (size_t)t*2097152 + hw;
  float s=0.f, ss=0.f;
  #pragma unroll 8
  for (int c=0;c<128;c++){ float v=base[(size_t)c*16384]; s+=v; ss+=v*v; }
  float mu  = s*0.0078125f;
  float var = fmaxf(ss*0.0078125f - mu*mu, 0.f);
  float rs  = rsqrtf(var + 1e-6f);
  unsigned int* op = (unsigned int*)(xf + (size_t)n*128);
  #pragma unroll 4
  for (int c=0;c<128;c+=2){
    float v0=(base[(size_t)c*16384]    -mu)*rs*g[c]  +b[c];
    float v1=(base[(size_t)(c+1)*16384]-mu)*rs*g[c+1]+b[c+1];
    op[c>>1]=packbf(v0,v1);
  }
}

// ---------- K5: LayerNorm over C, (N,C) bf16 row-major input ----------
__global__ __launch_bounds__(256) void k_ln_rows(const unsigned short* __restrict__ x,
                                                 const float* __restrict__ g,
                                                 const float* __restrict__ b,
                                                 unsigned short* __restrict__ y){
  int n = blockIdx.x*256 + threadIdx.x;
  const unsigned int* p = (const unsigned int*)(x + (size_t)n*128);
  float s=0.f, ss=0.f;
  #pragma unroll 8
  for (int j=0;j<64;j++){ unsigned int u=p[j]; float v0=bflo(u),v1=bfhi(u); s+=v0+v1; ss+=v0*v0+v1*v1; }
  float mu  = s*0.0078125f;
  float var = fmaxf(ss*0.0078125f - mu*mu, 0.f);
  float rs  = rsqrtf(var + 1e-6f);
  unsigned int* op=(unsigned int*)(y+(size_t)n*128);
  #pragma unroll 8
  for (int j=0;j<64;j++){
    unsigned int u=p[j];
    float v0=(bflo(u)-mu)*rs*g[2*j]  +b[2*j];
    float v1=(bfhi(u)-mu)*rs*g[2*j+1]+b[2*j+1];
    op[j]=packbf(v0,v1);
  }
}

// ---------- K2: QKV projections. 256 rows/block (4 m-tiles per wave).
// Weights pre-converted bf16 (q pre-scaled). q,k -> fp16; v -> fp8 e4m3.
// Mat order v,k,q so q-store (possible x alias) is last. ----
__global__ __launch_bounds__(256) void k_qkv(const unsigned short* xf,
                                             const unsigned short* __restrict__ wm,
                                             unsigned short* qf,
                                             unsigned short* __restrict__ kfo,
                                             unsigned short* __restrict__ vfo){
  __shared__ unsigned short wlds[16384];
  int wave = threadIdx.x>>6, lane = threadIdx.x&63;
  int m0w = blockIdx.x*256 + wave*64;
  int mrow = lane&15, quad = lane>>4;
  #pragma unroll 1
  for (int mi=0; mi<3; mi++){
    int mat = 2-mi;                       // v, k, q
    __syncthreads();
    { const uint4* src=(const uint4*)(wm + mat*16384);
      uint4* dst=(uint4*)wlds;
      #pragma unroll
      for (int i=0;i<8;i++) dst[threadIdx.x + 256*i] = src[threadIdx.x + 256*i]; }
    __syncthreads();
    #pragma unroll 1
    for (int mt=0; mt<4; mt++){
      int m0 = m0w + mt*16;
      bf16x8 a[4];
      const unsigned short* ap = xf + (size_t)(m0+mrow)*128 + quad*8;
      #pragma unroll
      for (int kc=0;kc<4;kc++) a[kc] = *(const bf16x8*)(ap + kc*32);
      for (int nt=0;nt<8;nt++){
        f32x4 acc = {0.f,0.f,0.f,0.f};
        #pragma unroll
        for (int kc=0;kc<4;kc++){
          bf16x8 bfr = *(const bf16x8*)(wlds + (nt*16+mrow)*128 + kc*32 + quad*8);
          acc = __builtin_amdgcn_mfma_f32_16x16x32_bf16(a[kc], bfr, acc, 0,0,0);
        }
        int col = nt*16+mrow;
        if (mat==2){
          // v: fp8 e4m3, 128 bytes per pixel row
          unsigned char* op8 = (unsigned char*)vfo + (size_t)(m0 + quad*4)*128 + col;
          #pragma unroll
          for (int r=0;r<4;r++){
            int pk = __builtin_amdgcn_cvt_pk_fp8_f32(acc[r], acc[r], 0, false);
            op8[(size_t)r*128] = (unsigned char)(pk & 0xff);
          }
        } else {
          unsigned short* out = (mat==0) ? qf : kfo;
          unsigned short* op = out + (size_t)(m0 + quad*4)*128 + col;
          #pragma unroll
          for (int r=0;r<4;r++) op[(size_t)r*128] = f2h(acc[r]);   // fp16 (q scale in W)
        }
      }
    }
  }
}

// ---------- K3: attention (R5 verbatim — best measured 167 µs).
// 2 threads/pixel-head, 16 ch each; fdot2 QK; exp2f; fp8 V PV;
// cross-row prefetch pipeline. Output bf16 normal order ----
__global__ __launch_bounds__(256) void k_attn(const unsigned short* qf,
                                              const unsigned short* __restrict__ kf,
                                              const unsigned short* __restrict__ vf,
                                              const float* __restrict__ flw,
                                              unsigned short* attf){
  int xcd = blockIdx.x & 7;
  int j   = blockIdx.x >> 3;      // 0..255
  int t       = j >> 6;           // 0..3
  int r       = j & 63;
  int h_local = r >> 2;           // 0..15
  int wq      = r & 3;            // 0..3
  int h = xcd*16 + h_local;
  int w = wq*32 + (threadIdx.x >> 3);
  int head  = (threadIdx.x >> 1) & 3;
  int cpart = threadIdx.x & 1;
  int hw = (h<<7) + w;
  int n  = (t<<14) + hw;
  float fh = flw[t*32768 + hw];
  float fw = flw[t*32768 + 16384 + hw];
  unsigned coff = head*32 + cpart*16;     // this thread's 16-channel slice
  const unsigned char* vf8 = (const unsigned char*)vf;   // fp8 rows, 128B/pixel
  const uint4* qp = (const uint4*)(qf + (size_t)n*128 + coff);
  uint4 q0v = qp[0], q1v = qp[1];
  unsigned qw[8] = {q0v.x,q0v.y,q0v.z,q0v.w,q1v.x,q1v.y,q1v.z,q1v.w};
  float acc[16];
  #pragma unroll
  for (int i=0;i<16;i++) acc[i]=0.f;
  float l = 0.f;

  // ---- per-dt window params (x = dt+1), all precomputed ----
  int rowb0, rowb1, rowb2;     // clamped ti << 14
  int hb0, hb1, hb2;           // h + oh(dt)
  int wm30, wm31, wm32;        // w + ow(dt) - 3
  int w0c0, w0c1, w0c2;        // clamp(wm3)
  {
    int ti;
    ti = t-1; ti = ti<0?0:ti;   rowb0 = ti<<14;
    rowb1 = t<<14;
    ti = t+1; ti = ti>3?3:ti;   rowb2 = ti<<14;
    int oh = (int)rintf(fh*(-1.0f)), ow = (int)rintf(fw*(-1.0f));
    hb0 = h+oh; wm30 = w+ow-3;
    hb1 = h;    wm31 = w-3;
    oh = (int)rintf(fh*(1.0f)); ow = (int)rintf(fw*(1.0f));
    hb2 = h+oh; wm32 = w+ow-3;
    w0c0 = wm30<0?0:(wm30>127?127:wm30);
    w0c1 = wm31<0?0:(wm31>127?127:wm31);
    w0c2 = wm32<0?0:(wm32>127?127:wm32);
  }

  // ---- pipeline prologue: first position (dt=-1, dh=-3, tap 0) ----
  uint4 ka0, ka1, va;
  {
    int hi0 = hb0-3; hi0 = hi0<0?0:(hi0>127?127:hi0);
    unsigned b0 = ((unsigned)(rowb0 + (hi0<<7) + w0c0)<<7) + coff;
    ka0 = ((const uint4*)(kf + b0))[0];
    ka1 = ((const uint4*)(kf + b0))[1];
    va  = *(const uint4*)(vf8 + b0);
  }

  #pragma unroll
  for (int x=0; x<3; x++){
    const int rb_t = (x==0)?rowb0:((x==1)?rowb1:rowb2);
    const int hb   = (x==0)?hb0:((x==1)?hb1:hb2);
    const int wm3  = (x==0)?wm30:((x==1)?wm31:wm32);
    const int w0c  = (x==0)?w0c0:((x==1)?w0c1:w0c2);
    // next-dt first-row params (compile-time selected; unused for x==2)
    const int nrb  = (x==0)?rowb1:rowb2;
    const int nhb  = (x==0)?hb1:hb2;
    const int nw0c = (x==0)?w0c1:w0c2;
    #pragma unroll 1
    for (int dh=-3; dh<=3; dh++){
      int hi = hb+dh; hi = hi<0?0:(hi>127?127:hi);
      int rbase = rb_t + (hi<<7);
      #pragma unroll
      for (int i=0;i<7;i++){
        // ---- compute next prefetch address ----
        unsigned bon;
        if (i<6){
          int wi = wm3+i+1; wi = wi<0?0:(wi>127?127:wi);
          bon = ((unsigned)(rbase + wi)<<7) + coff;
        } else if (dh<3){
          // next row of same dt, tap 0
          int hi2 = hb+dh+1; hi2 = hi2<0?0:(hi2>127?127:hi2);
          bon = ((unsigned)(rb_t + (hi2<<7) + w0c)<<7) + coff;
        } else if (x<2){
          // first row of next dt, tap 0
          int hi2 = nhb-3; hi2 = hi2<0?0:(hi2>127?127:hi2);
          bon = ((unsigned)(nrb + (hi2<<7) + nw0c)<<7) + coff;
        } else {
          bon = coff;     // final iteration: harmless dummy
        }
        uint4 kb0 = ((const uint4*)(kf + bon))[0];
        uint4 kb1 = ((const uint4*)(kf + bon))[1];
        uint4 vb  = *(const uint4*)(vf8 + bon);
        // ---- QK: two dot2 chains of 4 (16 channels in 8 VALU ops) ----
        float s0 = 0.f, s1 = 0.f;
        s0 = __builtin_amdgcn_fdot2(uh(qw[0]), uh(ka0.x), s0, false);
        s0 = __builtin_amdgcn_fdot2(uh(qw[1]), uh(ka0.y), s0, false);
        s0 = __builtin_amdgcn_fdot2(uh(qw[2]), uh(ka0.z), s0, false);
        s0 = __builtin_amdgcn_fdot2(uh(qw[3]), uh(ka0.w), s0, false);
        s1 = __builtin_amdgcn_fdot2(uh(qw[4]), uh(ka1.x), s1, false);
        s1 = __builtin_amdgcn_fdot2(uh(qw[5]), uh(ka1.y), s1, false);
        s1 = __builtin_amdgcn_fdot2(uh(qw[6]), uh(ka1.z), s1, false);
        s1 = __builtin_amdgcn_fdot2(uh(qw[7]), uh(ka1.w), s1, false);
        float s = s0 + s1;
        s += dpp_swap1(s);               // combine the two channel halves
        float e = exp2f(s);              // 2^s == exp(scale*(q.k)), log2e folded in q
        l += e;
        // ---- PV: decode 16 fp8 -> f32 pairs, FMA with e ----
        f32x2 c0 = __builtin_amdgcn_cvt_pk_f32_fp8((int)va.x, false);
        f32x2 c1 = __builtin_amdgcn_cvt_pk_f32_fp8((int)va.x, true);
        f32x2 c2 = __builtin_amdgcn_cvt_pk_f32_fp8((int)va.y, false);
        f32x2 c3 = __builtin_amdgcn_cvt_pk_f32_fp8((int)va.y, true);
        f32x2 c4 = __builtin_amdgcn_cvt_pk_f32_fp8((int)va.z, false);
        f32x2 c5 = __builtin_amdgcn_cvt_pk_f32_fp8((int)va.z, true);
        f32x2 c6 = __builtin_amdgcn_cvt_pk_f32_fp8((int)va.w, false);
        f32x2 c7 = __builtin_amdgcn_cvt_pk_f32_fp8((int)va.w, true);
        acc[0]  += e*c0.x; acc[1]  += e*c0.y;
        acc[2]  += e*c1.x; acc[3]  += e*c1.y;
        acc[4]  += e*c2.x; acc[5]  += e*c2.y;
        acc[6]  += e*c3.x; acc[7]  += e*c3.y;
        acc[8]  += e*c4.x; acc[9]  += e*c4.y;
        acc[10] += e*c5.x; acc[11] += e*c5.y;
        acc[12] += e*c6.x; acc[13] += e*c6.y;
        acc[14] += e*c7.x; acc[15] += e*c7.y;
        ka0=kb0; ka1=kb1; va=vb;
      }
    }
  }
  float inv = 1.f/l;
  unsigned int* op = (unsigned int*)(attf + (size_t)n*128 + coff);
  #pragma unroll
  for (int i=0;i<8;i++) op[i]=packbf(acc[2*i]*inv, acc[2*i+1]*inv);
}

// ---------- K4: Wo projection + residual. 256 rows/block, bf16 Wo from wm.
// vid1 may alias attf (reads of each m-tile precede its stores) ----
__global__ __launch_bounds__(256) void k_wo(const unsigned short* attf,
                                            const unsigned short* __restrict__ wm,
                                            const float* __restrict__ vid,
                                            unsigned short* vid1){
  __shared__ unsigned short wlds[16384];
  int wave = threadIdx.x>>6, lane = threadIdx.x&63;
  int m0w = blockIdx.x*256 + wave*64;
  int mrow = lane&15, quad = lane>>4;
  { const uint4* src=(const uint4*)(wm + 49152);
    uint4* dst=(uint4*)wlds;
    #pragma unroll
    for (int i=0;i<8;i++) dst[threadIdx.x + 256*i] = src[threadIdx.x + 256*i]; }
  __syncthreads();
  #pragma unroll 1
  for (int mt=0; mt<4; mt++){
    int m0 = m0w + mt*16;
    bf16x8 a[4];
    const unsigned short* ap = attf + (size_t)(m0+mrow)*128 + quad*8;
    #pragma unroll
    for (int kc=0;kc<4;kc++) a[kc] = *(const bf16x8*)(ap + kc*32);
    for (int nt=0;nt<8;nt++){
      f32x4 acc={0.f,0.f,0.f,0.f};
      #pragma unroll
      for (int kc=0;kc<4;kc++){
        bf16x8 bfr = *(const bf16x8*)(wlds + (nt*16+mrow)*128 + kc*32 + quad*8);
        acc = __builtin_amdgcn_mfma_f32_16x16x32_bf16(a[kc], bfr, acc, 0,0,0);
      }
      int col = nt*16+mrow;
      #pragma unroll
      for (int r=0;r<4;r++){
        int nrow = m0 + quad*4 + r;
        int tt = nrow>>14, hww = nrow&16383;
        float resid = vid[(size_t)tt*2097152 + (size_t)col*16384 + hww];
        vid1[(size_t)nrow*128 + col] = f2b(resid + acc[r]);
      }
    }
  }
}

// ---------- K6/K7 shared conv core (merged out-channel halves) ----------
// Block = (frame, row h). M=128 (full row), N=128 (ALL out channels).
// Full 128x128 tap weight staged in 32KB LDS; next tap prefetched into
// 8 uint4 VGPRs during compute. A-fragments loaded once per tap serve all
// 8 n-tiles (half the VMEM per MFMA vs the chalf-split version).
#define CONV_PROLOG \
  __shared__ unsigned short wlds[16384]; \
  int wv = threadIdx.x>>6, lane = threadIdx.x&63; \
  int mrow = lane&15, quad = lane>>4; \
  int h = blockIdx.x & 127; \
  int frame = blockIdx.x>>7; \
  size_t nf = (size_t)frame*16384; \
  f32x4 accA[8], accB[8]; \
  _Pragma("unroll") \
  for (int i=0;i<8;i++){ accA[i]=(f32x4){0.f,0.f,0.f,0.f}; accB[i]=(f32x4){0.f,0.f,0.f,0.f}; } \
  { const uint4* sp=(const uint4*)(wtap); \
    uint4 st[8]; \
    _Pragma("unroll") \
    for (int i=0;i<8;i++) st[i]=sp[threadIdx.x+256*i]; \
    uint4* d4=(uint4*)wlds; \
    _Pragma("unroll") \
    for (int i=0;i<8;i++) d4[threadIdx.x+256*i]=st[i]; } \
  __syncthreads(); \
  _Pragma("unroll 1") \
  for (int tap=0; tap<9; tap++){ \
    uint4 st[8]; \
    if (tap<8){ const uint4* sp=(const uint4*)(wtap + (size_t)(tap+1)*16384); \
      _Pragma("unroll") \
      for (int i=0;i<8;i++) st[i]=sp[threadIdx.x+256*i]; } \
    int ky=tap/3, kx=tap-3*ky; \
    int h2c=h+ky-1; \
    if ((unsigned)h2c<128u){ \
      int wA = wv*32 + mrow + kx - 1;            /* [-1,112] */ \
      int wAc = wA < 0 ? 0 : wA; \
      int wB = wA + 16;                          /* [15,128] */ \
      int wBc = wB > 127 ? 127 : wB; \
      const unsigned short* rowp = src + (nf + (size_t)h2c*128)*128 + quad*8; \
      const unsigned short* apA = rowp + (size_t)wAc*128; \
      const unsigned short* apB = rowp + (size_t)wBc*128; \
      bf16x8 aA[4], aB[4]; \
      _Pragma("unroll") \
      for (int kc=0;kc<4;kc++){ aA[kc]=*(const bf16x8*)(apA+kc*32); aB[kc]=*(const bf16x8*)(apB+kc*32); } \
      if (kx==0 && wv==0 && mrow==0){ _Pragma("unroll") for (int kc=0;kc<4;kc++) aA[kc]=(bf16x8){0,0,0,0,0,0,0,0}; } \
      if (kx==2 && wv==3 && mrow==15){ _Pragma("unroll") for (int kc=0;kc<4;kc++) aB[kc]=(bf16x8){0,0,0,0,0,0,0,0}; } \
      _Pragma("unroll") \
      for (int nt=0;nt<8;nt++){ \
        _Pragma("unroll") \
        for (int kc=0;kc<4;kc++){ \
          bf16x8 bfr=*(const bf16x8*)(wlds + (nt*16+mrow)*128 + kc*32 + quad*8); \
          accA[nt]=__builtin_amdgcn_mfma_f32_16x16x32_bf16(aA[kc],bfr,accA[nt],0,0,0); \
          accB[nt]=__builtin_amdgcn_mfma_f32_16x16x32_bf16(aB[kc],bfr,accB[nt],0,0,0); \
        } \
      } \
    } \
    __syncthreads(); \
    if (tap<8){ uint4* d4=(uint4*)wlds; \
      _Pragma("unroll") \
      for (int i=0;i<8;i++) d4[threadIdx.x+256*i]=st[i]; \
      __syncthreads(); } \
  }

// ---------- K6: 3x3 conv + bias + tanh-GELU, (N,C) bf16 out ----------
__global__ __launch_bounds__(256) void k_conv_gelu(const unsigned short* __restrict__ src,
                                                   const unsigned short* __restrict__ wtap,
                                                   const float* __restrict__ bias,
                                                   unsigned short* __restrict__ dst){
  CONV_PROLOG
  #pragma unroll
  for (int nt=0;nt<8;nt++){
    int col = nt*16 + mrow;
    float bb = bias[col];
    #pragma unroll
    for (int r=0;r<4;r++){
      int pA = h*128 + wv*32 + quad*4 + r;
      float xA = accA[nt][r]+bb;
      float zA = 0.7978845608028654f*(xA+0.044715f*xA*xA*xA);
      dst[(nf+(size_t)pA)*128+col] = f2b(xA * __builtin_amdgcn_rcpf(1.f + __expf(-2.f*zA)));
      float xB = accB[nt][r]+bb;
      float zB = 0.7978845608028654f*(xB+0.044715f*xB*xB*xB);
      dst[(nf+(size_t)(pA+16))*128+col] = f2b(xB * __builtin_amdgcn_rcpf(1.f + __expf(-2.f*zB)));
    }
  }
}

// ---------- K7: 3x3 conv + bias + (vid1 + yb + r) -> d_out fp32 NCHW ----------
__global__ __launch_bounds__(256) void k_conv_final(const unsigned short* __restrict__ src,
                                                    const unsigned short* __restrict__ wtap,
                                                    const float* __restrict__ bias,
                                                    const unsigned short* __restrict__ yb,
                                                    const unsigned short* __restrict__ vid1,
                                                    float* __restrict__ out){
  CONV_PROLOG
  #pragma unroll
  for (int nt=0;nt<8;nt++){
    int col = nt*16 + mrow;
    float bb = bias[col];
    #pragma unroll
    for (int r=0;r<4;r++){
      int pA = h*128 + wv*32 + quad*4 + r;
      size_t rowA = nf+(size_t)pA, rowB = rowA+16;
      float xA = accA[nt][r]+bb;
      out[(size_t)frame*2097152 + (size_t)col*16384 + pA] =
        b2f(vid1[rowA*128+col]) + b2f(yb[rowA*128+col]) + xA;
      float xB = accB[nt][r]+bb;
      out[(size_t)frame*2097152 + (size_t)col*16384 + pA + 16] =
        b2f(vid1[rowB*128+col]) + b2f(yb[rowB*128+col]) + xB;
    }
  }
}

extern "C" void kernel_launch(void* const* d_in, const int* in_sizes, int n_in,
                              void* d_out, int out_size, void* d_ws, size_t ws_size,
                              hipStream_t stream) {
  const float* vid  = (const float*)d_in[0];
  const float* flw  = (const float*)d_in[1];
  const float* g0   = (const float*)d_in[2];
  const float* b0   = (const float*)d_in[3];
  const float* Wq   = (const float*)d_in[4];
  const float* Wk   = (const float*)d_in[5];
  const float* Wv   = (const float*)d_in[6];
  const float* Wo   = (const float*)d_in[7];
  const float* g1   = (const float*)d_in[8];
  const float* b1   = (const float*)d_in[9];
  const float* wr1  = (const float*)d_in[10];
  const float* br1  = (const float*)d_in[11];
  const float* wr2  = (const float*)d_in[12];
  const float* br2  = (const float*)d_in[13];
  float* out = (float*)d_out;

  unsigned short* A  = (unsigned short*)d_ws;
  unsigned short* Bs = A + SLOT_ELEMS;
  unsigned short* Cs = Bs + SLOT_ELEMS;
  bool four = ws_size >= (size_t)4*SLOT_ELEMS*2 + 2*294912;
  unsigned short* D  = four ? (Cs + SLOT_ELEMS) : A;   // q/att/vid1 slot
  unsigned short* wt1 = Cs + SLOT_ELEMS + (four ? SLOT_ELEMS : 0);
  unsigned short* wt2 = wt1 + 147456;
  unsigned short* wm  = Cs + WM_OFF;   // bf16 proj mats in free upper half of Cs (v-fp8 uses lower 8MB)

  k_wprep   <<<832, 256, 0, stream>>>(wr1, wr2, Wq, Wk, Wv, Wo, wt1, wt2, wm);
  k_ln_nchw <<<256, 256, 0, stream>>>(vid, g0, b0, A);
  k_qkv     <<<256, 256, 0, stream>>>(A, wm, D, Bs, Cs);
  k_attn    <<<2048,256, 0, stream>>>(D, Bs, Cs, flw, D);
  k_wo      <<<256, 256, 0, stream>>>(D, wm, vid, D);
  k_ln_rows <<<256, 256, 0, stream>>>(D, g1, b1, Bs);
  k_conv_gelu <<<512,256,0, stream>>>(Bs, wt1, br1, Cs);
  k_conv_final<<<512,256,0, stream>>>(Cs, wt2, br2, Bs, D, out);
}

// Round 9
// 445.485 us; speedup vs baseline: 1.0640x; 1.0640x over previous
//
#include <hip/hip_runtime.h>

// ---------- bf16 helpers (bit-level, RNE) ----------
__device__ __forceinline__ float bflo(unsigned int u){ return __builtin_bit_cast(float, (unsigned int)(u<<16)); }
__device__ __forceinline__ float bfhi(unsigned int u){ return __builtin_bit_cast(float, (unsigned int)(u & 0xffff0000u)); }
__device__ __forceinline__ float b2f(unsigned short s){ return __builtin_bit_cast(float, ((unsigned int)s)<<16); }
__device__ __forceinline__ unsigned short f2b(float f){
  unsigned int x = __builtin_bit_cast(unsigned int, f);
  x += 0x7fffu + ((x>>16)&1u);
  return (unsigned short)(x>>16);
}
__device__ __forceinline__ unsigned int packbf(float a, float b){
  return (unsigned int)f2b(a) | ((unsigned int)f2b(b)<<16);
}
__device__ __forceinline__ unsigned short f2h(float f){
  return __builtin_bit_cast(unsigned short, (_Float16)f);
}
__device__ __forceinline__ float dpp_swap1(float s){
  int so = __builtin_amdgcn_mov_dpp(__builtin_bit_cast(int, s), 0xB1, 0xF, 0xF, true); // quad_perm [1,0,3,2]
  return __builtin_bit_cast(float, so);
}
// LDS XOR swizzle: kills the 16-bank aliasing of 256B-stride row reads.
// Involution on byte addresses; applied to BOTH write and read sides.
__device__ __forceinline__ unsigned swz(unsigned b){ return b ^ (((b>>8)&7u)<<4); }

using bf16x8 = __attribute__((ext_vector_type(8))) short;
using f32x4  = __attribute__((ext_vector_type(4))) float;
using f32x2  = __attribute__((ext_vector_type(2))) float;
using h2     = __attribute__((ext_vector_type(2))) _Float16;

__device__ __forceinline__ h2 uh(unsigned int u){ return __builtin_bit_cast(h2, u); }

#define NPOS 65536          // T*H*W
#define SLOT_ELEMS 8388608  // NPOS*128 bf16 elements
#define WM_OFF 6291456      // wm offset (shorts) inside Cs slot (v-fp8 uses first 4194304)

// ---------- K0: conv weights fp32 (O,C,3,3) -> bf16 (tap,O,C);
// projection mats Wq(+scale),Wk,Wv,Wo fp32 -> bf16 [mat][o][c] ----
__global__ __launch_bounds__(256) void k_wprep(const float* __restrict__ w1,
                                               const float* __restrict__ w2,
                                               const float* __restrict__ Wq,
                                               const float* __restrict__ Wk,
                                               const float* __restrict__ Wv,
                                               const float* __restrict__ Wo,
                                               unsigned short* __restrict__ o1,
                                               unsigned short* __restrict__ o2,
                                               unsigned short* __restrict__ wm){
  int idx = blockIdx.x*256 + threadIdx.x;
  if (idx < 147456){
    int o = idx / 1152;
    int rem = idx - o*1152;
    int c = rem / 9;
    int tap = rem - c*9;
    int dsti = tap*16384 + o*128 + c;
    o1[dsti] = f2b(w1[idx]);
    o2[dsti] = f2b(w2[idx]);
  } else if (idx < 212992){
    int idx2 = idx - 147456;
    int mat = idx2 >> 14;
    int ij  = idx2 & 16383;
    // q scale = (1/sqrt(32)) * log2(e) folded into Wq
    float v = (mat==0) ? Wq[ij]*0.2550348613f
            : (mat==1) ? Wk[ij]
            : (mat==2) ? Wv[ij] : Wo[ij];
    wm[idx2] = f2b(v);
  }
}

// ---------- K1: LayerNorm over C, fp32 NCHW input -> (N,C) bf16 ----------
__global__ __launch_bounds__(256) void k_ln_nchw(const float* __restrict__ vid,
                                                 const float* __restrict__ g,
                                                 const float* __restrict__ b,
                                                 unsigned short* __restrict__ xf){
  int n = blockIdx.x*256 + threadIdx.x;
  int t = n >> 14, hw = n & 16383;
  const float* base = vid + (size_t)t*2097152 + hw;
  float s=0.f, ss=0.f;
  #pragma unroll 8
  for (int c=0;c<128;c++){ float v=base[(size_t)c*16384]; s+=v; ss+=v*v; }
  float mu  = s*0.0078125f;
  float var = fmaxf(ss*0.0078125f - mu*mu, 0.f);
  float rs  = rsqrtf(var + 1e-6f);
  unsigned int* op = (unsigned int*)(xf + (size_t)n*128);
  #pragma unroll 4
  for (int c=0;c<128;c+=2){
    float v0=(base[(size_t)c*16384]    -mu)*rs*g[c]  +b[c];
    float v1=(base[(size_t)(c+1)*16384]-mu)*rs*g[c+1]+b[c+1];
    op[c>>1]=packbf(v0,v1);
  }
}

// ---------- K5: LayerNorm over C, (N,C) bf16 row-major input ----------
__global__ __launch_bounds__(256) void k_ln_rows(const unsigned short* __restrict__ x,
                                                 const float* __restrict__ g,
                                                 const float* __restrict__ b,
                                                 unsigned short* __restrict__ y){
  int n = blockIdx.x*256 + threadIdx.x;
  const unsigned int* p = (const unsigned int*)(x + (size_t)n*128);
  float s=0.f, ss=0.f;
  #pragma unroll 8
  for (int j=0;j<64;j++){ unsigned int u=p[j]; float v0=bflo(u),v1=bfhi(u); s+=v0+v1; ss+=v0*v0+v1*v1; }
  float mu  = s*0.0078125f;
  float var = fmaxf(ss*0.0078125f - mu*mu, 0.f);
  float rs  = rsqrtf(var + 1e-6f);
  unsigned int* op=(unsigned int*)(y+(size_t)n*128);
  #pragma unroll 8
  for (int j=0;j<64;j++){
    unsigned int u=p[j];
    float v0=(bflo(u)-mu)*rs*g[2*j]  +b[2*j];
    float v1=(bfhi(u)-mu)*rs*g[2*j+1]+b[2*j+1];
    op[j]=packbf(v0,v1);
  }
}

// ---------- K2: QKV projections. 256 rows/block (4 m-tiles per wave).
// Weights pre-converted bf16 (q pre-scaled), LDS XOR-swizzled.
// q,k -> fp16; v -> fp8 e4m3. Mat order v,k,q (q-store last; may alias x) ----
__global__ __launch_bounds__(256) void k_qkv(const unsigned short* xf,
                                             const unsigned short* __restrict__ wm,
                                             unsigned short* qf,
                                             unsigned short* __restrict__ kfo,
                                             unsigned short* __restrict__ vfo){
  __shared__ unsigned short wlds[16384];
  int wave = threadIdx.x>>6, lane = threadIdx.x&63;
  int m0w = blockIdx.x*256 + wave*64;
  int mrow = lane&15, quad = lane>>4;
  #pragma unroll 1
  for (int mi=0; mi<3; mi++){
    int mat = 2-mi;                       // v, k, q
    __syncthreads();
    { const uint4* src=(const uint4*)(wm + mat*16384);
      #pragma unroll
      for (int i=0;i<8;i++){
        unsigned bb=(threadIdx.x+256*i)*16;
        *(uint4*)((char*)wlds + swz(bb)) = src[threadIdx.x+256*i];
      } }
    __syncthreads();
    #pragma unroll 1
    for (int mt=0; mt<4; mt++){
      int m0 = m0w + mt*16;
      bf16x8 a[4];
      const unsigned short* ap = xf + (size_t)(m0+mrow)*128 + quad*8;
      #pragma unroll
      for (int kc=0;kc<4;kc++) a[kc] = *(const bf16x8*)(ap + kc*32);
      for (int nt=0;nt<8;nt++){
        f32x4 acc = {0.f,0.f,0.f,0.f};
        #pragma unroll
        for (int kc=0;kc<4;kc++){
          bf16x8 bfr = *(const bf16x8*)((const char*)wlds + swz((nt*16+mrow)*256 + kc*64 + quad*16));
          acc = __builtin_amdgcn_mfma_f32_16x16x32_bf16(a[kc], bfr, acc, 0,0,0);
        }
        int col = nt*16+mrow;
        if (mat==2){
          // v: fp8 e4m3, 128 bytes per pixel row
          unsigned char* op8 = (unsigned char*)vfo + (size_t)(m0 + quad*4)*128 + col;
          #pragma unroll
          for (int r=0;r<4;r++){
            int pk = __builtin_amdgcn_cvt_pk_fp8_f32(acc[r], acc[r], 0, false);
            op8[(size_t)r*128] = (unsigned char)(pk & 0xff);
          }
        } else {
          unsigned short* out = (mat==0) ? qf : kfo;
          unsigned short* op = out + (size_t)(m0 + quad*4)*128 + col;
          #pragma unroll
          for (int r=0;r<4;r++) op[(size_t)r*128] = f2h(acc[r]);   // fp16 (q scale in W)
        }
      }
    }
  }
}

// ---------- K3: attention (R5 verbatim — best measured 167 µs).
// 2 threads/pixel-head, 16 ch each; fdot2 QK; exp2f; fp8 V PV;
// cross-row prefetch pipeline. Output bf16 normal order ----
__global__ __launch_bounds__(256) void k_attn(const unsigned short* qf,
                                              const unsigned short* __restrict__ kf,
                                              const unsigned short* __restrict__ vf,
                                              const float* __restrict__ flw,
                                              unsigned short* attf){
  int xcd = blockIdx.x & 7;
  int j   = blockIdx.x >> 3;      // 0..255
  int t       = j >> 6;           // 0..3
  int r       = j & 63;
  int h_local = r >> 2;           // 0..15
  int wq      = r & 3;            // 0..3
  int h = xcd*16 + h_local;
  int w = wq*32 + (threadIdx.x >> 3);
  int head  = (threadIdx.x >> 1) & 3;
  int cpart = threadIdx.x & 1;
  int hw = (h<<7) + w;
  int n  = (t<<14) + hw;
  float fh = flw[t*32768 + hw];
  float fw = flw[t*32768 + 16384 + hw];
  unsigned coff = head*32 + cpart*16;     // this thread's 16-channel slice
  const unsigned char* vf8 = (const unsigned char*)vf;   // fp8 rows, 128B/pixel
  const uint4* qp = (const uint4*)(qf + (size_t)n*128 + coff);
  uint4 q0v = qp[0], q1v = qp[1];
  unsigned qw[8] = {q0v.x,q0v.y,q0v.z,q0v.w,q1v.x,q1v.y,q1v.z,q1v.w};
  float acc[16];
  #pragma unroll
  for (int i=0;i<16;i++) acc[i]=0.f;
  float l = 0.f;

  // ---- per-dt window params (x = dt+1), all precomputed ----
  int rowb0, rowb1, rowb2;     // clamped ti << 14
  int hb0, hb1, hb2;           // h + oh(dt)
  int wm30, wm31, wm32;        // w + ow(dt) - 3
  int w0c0, w0c1, w0c2;        // clamp(wm3)
  {
    int ti;
    ti = t-1; ti = ti<0?0:ti;   rowb0 = ti<<14;
    rowb1 = t<<14;
    ti = t+1; ti = ti>3?3:ti;   rowb2 = ti<<14;
    int oh = (int)rintf(fh*(-1.0f)), ow = (int)rintf(fw*(-1.0f));
    hb0 = h+oh; wm30 = w+ow-3;
    hb1 = h;    wm31 = w-3;
    oh = (int)rintf(fh*(1.0f)); ow = (int)rintf(fw*(1.0f));
    hb2 = h+oh; wm32 = w+ow-3;
    w0c0 = wm30<0?0:(wm30>127?127:wm30);
    w0c1 = wm31<0?0:(wm31>127?127:wm31);
    w0c2 = wm32<0?0:(wm32>127?127:wm32);
  }

  // ---- pipeline prologue: first position (dt=-1, dh=-3, tap 0) ----
  uint4 ka0, ka1, va;
  {
    int hi0 = hb0-3; hi0 = hi0<0?0:(hi0>127?127:hi0);
    unsigned b0 = ((unsigned)(rowb0 + (hi0<<7) + w0c0)<<7) + coff;
    ka0 = ((const uint4*)(kf + b0))[0];
    ka1 = ((const uint4*)(kf + b0))[1];
    va  = *(const uint4*)(vf8 + b0);
  }

  #pragma unroll
  for (int x=0; x<3; x++){
    const int rb_t = (x==0)?rowb0:((x==1)?rowb1:rowb2);
    const int hb   = (x==0)?hb0:((x==1)?hb1:hb2);
    const int wm3  = (x==0)?wm30:((x==1)?wm31:wm32);
    const int w0c  = (x==0)?w0c0:((x==1)?w0c1:w0c2);
    // next-dt first-row params (compile-time selected; unused for x==2)
    const int nrb  = (x==0)?rowb1:rowb2;
    const int nhb  = (x==0)?hb1:hb2;
    const int nw0c = (x==0)?w0c1:w0c2;
    #pragma unroll 1
    for (int dh=-3; dh<=3; dh++){
      int hi = hb+dh; hi = hi<0?0:(hi>127?127:hi);
      int rbase = rb_t + (hi<<7);
      #pragma unroll
      for (int i=0;i<7;i++){
        // ---- compute next prefetch address ----
        unsigned bon;
        if (i<6){
          int wi = wm3+i+1; wi = wi<0?0:(wi>127?127:wi);
          bon = ((unsigned)(rbase + wi)<<7) + coff;
        } else if (dh<3){
          // next row of same dt, tap 0
          int hi2 = hb+dh+1; hi2 = hi2<0?0:(hi2>127?127:hi2);
          bon = ((unsigned)(rb_t + (hi2<<7) + w0c)<<7) + coff;
        } else if (x<2){
          // first row of next dt, tap 0
          int hi2 = nhb-3; hi2 = hi2<0?0:(hi2>127?127:hi2);
          bon = ((unsigned)(nrb + (hi2<<7) + nw0c)<<7) + coff;
        } else {
          bon = coff;     // final iteration: harmless dummy
        }
        uint4 kb0 = ((const uint4*)(kf + bon))[0];
        uint4 kb1 = ((const uint4*)(kf + bon))[1];
        uint4 vb  = *(const uint4*)(vf8 + bon);
        // ---- QK: two dot2 chains of 4 (16 channels in 8 VALU ops) ----
        float s0 = 0.f, s1 = 0.f;
        s0 = __builtin_amdgcn_fdot2(uh(qw[0]), uh(ka0.x), s0, false);
        s0 = __builtin_amdgcn_fdot2(uh(qw[1]), uh(ka0.y), s0, false);
        s0 = __builtin_amdgcn_fdot2(uh(qw[2]), uh(ka0.z), s0, false);
        s0 = __builtin_amdgcn_fdot2(uh(qw[3]), uh(ka0.w), s0, false);
        s1 = __builtin_amdgcn_fdot2(uh(qw[4]), uh(ka1.x), s1, false);
        s1 = __builtin_amdgcn_fdot2(uh(qw[5]), uh(ka1.y), s1, false);
        s1 = __builtin_amdgcn_fdot2(uh(qw[6]), uh(ka1.z), s1, false);
        s1 = __builtin_amdgcn_fdot2(uh(qw[7]), uh(ka1.w), s1, false);
        float s = s0 + s1;
        s += dpp_swap1(s);               // combine the two channel halves
        float e = exp2f(s);              // 2^s == exp(scale*(q.k)), log2e folded in q
        l += e;
        // ---- PV: decode 16 fp8 -> f32 pairs, FMA with e ----
        f32x2 c0 = __builtin_amdgcn_cvt_pk_f32_fp8((int)va.x, false);
        f32x2 c1 = __builtin_amdgcn_cvt_pk_f32_fp8((int)va.x, true);
        f32x2 c2 = __builtin_amdgcn_cvt_pk_f32_fp8((int)va.y, false);
        f32x2 c3 = __builtin_amdgcn_cvt_pk_f32_fp8((int)va.y, true);
        f32x2 c4 = __builtin_amdgcn_cvt_pk_f32_fp8((int)va.z, false);
        f32x2 c5 = __builtin_amdgcn_cvt_pk_f32_fp8((int)va.z, true);
        f32x2 c6 = __builtin_amdgcn_cvt_pk_f32_fp8((int)va.w, false);
        f32x2 c7 = __builtin_amdgcn_cvt_pk_f32_fp8((int)va.w, true);
        acc[0]  += e*c0.x; acc[1]  += e*c0.y;
        acc[2]  += e*c1.x; acc[3]  += e*c1.y;
        acc[4]  += e*c2.x; acc[5]  += e*c2.y;
        acc[6]  += e*c3.x; acc[7]  += e*c3.y;
        acc[8]  += e*c4.x; acc[9]  += e*c4.y;
        acc[10] += e*c5.x; acc[11] += e*c5.y;
        acc[12] += e*c6.x; acc[13] += e*c6.y;
        acc[14] += e*c7.x; acc[15] += e*c7.y;
        ka0=kb0; ka1=kb1; va=vb;
      }
    }
  }
  float inv = 1.f/l;
  unsigned int* op = (unsigned int*)(attf + (size_t)n*128 + coff);
  #pragma unroll
  for (int i=0;i<8;i++) op[i]=packbf(acc[2*i]*inv, acc[2*i+1]*inv);
}

// ---------- K4: Wo projection + residual. 256 rows/block, bf16 Wo from wm,
// LDS XOR-swizzled. vid1 may alias attf ----
__global__ __launch_bounds__(256) void k_wo(const unsigned short* attf,
                                            const unsigned short* __restrict__ wm,
                                            const float* __restrict__ vid,
                                            unsigned short* vid1){
  __shared__ unsigned short wlds[16384];
  int wave = threadIdx.x>>6, lane = threadIdx.x&63;
  int m0w = blockIdx.x*256 + wave*64;
  int mrow = lane&15, quad = lane>>4;
  { const uint4* src=(const uint4*)(wm + 49152);
    #pragma unroll
    for (int i=0;i<8;i++){
      unsigned bb=(threadIdx.x+256*i)*16;
      *(uint4*)((char*)wlds + swz(bb)) = src[threadIdx.x+256*i];
    } }
  __syncthreads();
  #pragma unroll 1
  for (int mt=0; mt<4; mt++){
    int m0 = m0w + mt*16;
    bf16x8 a[4];
    const unsigned short* ap = attf + (size_t)(m0+mrow)*128 + quad*8;
    #pragma unroll
    for (int kc=0;kc<4;kc++) a[kc] = *(const bf16x8*)(ap + kc*32);
    for (int nt=0;nt<8;nt++){
      f32x4 acc={0.f,0.f,0.f,0.f};
      #pragma unroll
      for (int kc=0;kc<4;kc++){
        bf16x8 bfr = *(const bf16x8*)((const char*)wlds + swz((nt*16+mrow)*256 + kc*64 + quad*16));
        acc = __builtin_amdgcn_mfma_f32_16x16x32_bf16(a[kc], bfr, acc, 0,0,0);
      }
      int col = nt*16+mrow;
      #pragma unroll
      for (int r=0;r<4;r++){
        int nrow = m0 + quad*4 + r;
        int tt = nrow>>14, hww = nrow&16383;
        float resid = vid[(size_t)tt*2097152 + (size_t)col*16384 + hww];
        vid1[(size_t)nrow*128 + col] = f2b(resid + acc[r]);
      }
    }
  }
}

// ---------- K6/K7 shared conv core (R7 chalf-split + LDS XOR swizzle) ----------
// Block = (frame, row h, col-half). M=128 (full row), 64 out channels.
// Per wave: 2 m-tiles of 16 share every B-fragment ds_read (2 MFMA per read).
// Weights for tap t+1 prefetched into 16 VGPRs during tap t compute; 16KB LDS.
#define CONV_PROLOG \
  __shared__ unsigned short wlds[8192]; \
  int wv = threadIdx.x>>6, lane = threadIdx.x&63; \
  int mrow = lane&15, quad = lane>>4; \
  int chalf = blockIdx.x & 1; \
  int h = (blockIdx.x>>1) & 127; \
  int frame = blockIdx.x>>8; \
  size_t nf = (size_t)frame*16384; \
  f32x4 accA[4], accB[4]; \
  _Pragma("unroll") \
  for (int i=0;i<4;i++){ accA[i]=(f32x4){0.f,0.f,0.f,0.f}; accB[i]=(f32x4){0.f,0.f,0.f,0.f}; } \
  { const uint4* sp=(const uint4*)(wtap + chalf*8192); \
    uint4 s0=sp[threadIdx.x], s1=sp[threadIdx.x+256], s2=sp[threadIdx.x+512], s3=sp[threadIdx.x+768]; \
    unsigned b0=(unsigned)threadIdx.x*16; \
    *(uint4*)((char*)wlds + swz(b0))         = s0; \
    *(uint4*)((char*)wlds + swz(b0+4096u))   = s1; \
    *(uint4*)((char*)wlds + swz(b0+8192u))   = s2; \
    *(uint4*)((char*)wlds + swz(b0+12288u))  = s3; } \
  __syncthreads(); \
  _Pragma("unroll 1") \
  for (int tap=0; tap<9; tap++){ \
    uint4 s0,s1,s2,s3; \
    if (tap<8){ const uint4* sp=(const uint4*)(wtap + (size_t)(tap+1)*16384 + chalf*8192); \
      s0=sp[threadIdx.x]; s1=sp[threadIdx.x+256]; s2=sp[threadIdx.x+512]; s3=sp[threadIdx.x+768]; } \
    int ky=tap/3, kx=tap-3*ky; \
    int h2c=h+ky-1; \
    if ((unsigned)h2c<128u){ \
      int wA = wv*32 + mrow + kx - 1;            /* [-1,112] */ \
      int wAc = wA < 0 ? 0 : wA; \
      int wB = wA + 16;                          /* [15,128] */ \
      int wBc = wB > 127 ? 127 : wB; \
      const unsigned short* rowp = src + (nf + (size_t)h2c*128)*128 + quad*8; \
      const unsigned short* apA = rowp + (size_t)wAc*128; \
      const unsigned short* apB = rowp + (size_t)wBc*128; \
      bf16x8 aA[4], aB[4]; \
      _Pragma("unroll") \
      for (int kc=0;kc<4;kc++){ aA[kc]=*(const bf16x8*)(apA+kc*32); aB[kc]=*(const bf16x8*)(apB+kc*32); } \
      if (kx==0 && wv==0 && mrow==0){ _Pragma("unroll") for (int kc=0;kc<4;kc++) aA[kc]=(bf16x8){0,0,0,0,0,0,0,0}; } \
      if (kx==2 && wv==3 && mrow==15){ _Pragma("unroll") for (int kc=0;kc<4;kc++) aB[kc]=(bf16x8){0,0,0,0,0,0,0,0}; } \
      _Pragma("unroll") \
      for (int nt=0;nt<4;nt++){ \
        _Pragma("unroll") \
        for (int kc=0;kc<4;kc++){ \
          bf16x8 bfr=*(const bf16x8*)((const char*)wlds + swz((nt*16+mrow)*256 + kc*64 + quad*16)); \
          accA[nt]=__builtin_amdgcn_mfma_f32_16x16x32_bf16(aA[kc],bfr,accA[nt],0,0,0); \
          accB[nt]=__builtin_amdgcn_mfma_f32_16x16x32_bf16(aB[kc],bfr,accB[nt],0,0,0); \
        } \
      } \
    } \
    __syncthreads(); \
    if (tap<8){ unsigned b0=(unsigned)threadIdx.x*16; \
      *(uint4*)((char*)wlds + swz(b0))         = s0; \
      *(uint4*)((char*)wlds + swz(b0+4096u))   = s1; \
      *(uint4*)((char*)wlds + swz(b0+8192u))   = s2; \
      *(uint4*)((char*)wlds + swz(b0+12288u))  = s3; \
      __syncthreads(); } \
  }

// ---------- K6: 3x3 conv + bias + tanh-GELU, (N,C) bf16 out ----------
__global__ __launch_bounds__(256) void k_conv_gelu(const unsigned short* __restrict__ src,
                                                   const unsigned short* __restrict__ wtap,
                                                   const float* __restrict__ bias,
                                                   unsigned short* __restrict__ dst){
  CONV_PROLOG
  #pragma unroll
  for (int nt=0;nt<4;nt++){
    int col = chalf*64 + nt*16 + mrow;
    float bb = bias[col];
    #pragma unroll
    for (int r=0;r<4;r++){
      int pA = h*128 + wv*32 + quad*4 + r;
      float xA = accA[nt][r]+bb;
      float zA = 0.7978845608028654f*(xA+0.044715f*xA*xA*xA);
      dst[(nf+(size_t)pA)*128+col] = f2b(xA * __builtin_amdgcn_rcpf(1.f + __expf(-2.f*zA)));
      float xB = accB[nt][r]+bb;
      float zB = 0.7978845608028654f*(xB+0.044715f*xB*xB*xB);
      dst[(nf+(size_t)(pA+16))*128+col] = f2b(xB * __builtin_amdgcn_rcpf(1.f + __expf(-2.f*zB)));
    }
  }
}

// ---------- K7: 3x3 conv + bias + (vid1 + yb + r) -> d_out fp32 NCHW ----------
__global__ __launch_bounds__(256) void k_conv_final(const unsigned short* __restrict__ src,
                                                    const unsigned short* __restrict__ wtap,
                                                    const float* __restrict__ bias,
                                                    const unsigned short* __restrict__ yb,
                                                    const unsigned short* __restrict__ vid1,
                                                    float* __restrict__ out){
  CONV_PROLOG
  #pragma unroll
  for (int nt=0;nt<4;nt++){
    int col = chalf*64 + nt*16 + mrow;
    float bb = bias[col];
    #pragma unroll
    for (int r=0;r<4;r++){
      int pA = h*128 + wv*32 + quad*4 + r;
      size_t rowA = nf+(size_t)pA, rowB = rowA+16;
      float xA = accA[nt][r]+bb;
      out[(size_t)frame*2097152 + (size_t)col*16384 + pA] =
        b2f(vid1[rowA*128+col]) + b2f(yb[rowA*128+col]) + xA;
      float xB = accB[nt][r]+bb;
      out[(size_t)frame*2097152 + (size_t)col*16384 + pA + 16] =
        b2f(vid1[rowB*128+col]) + b2f(yb[rowB*128+col]) + xB;
    }
  }
}

extern "C" void kernel_launch(void* const* d_in, const int* in_sizes, int n_in,
                              void* d_out, int out_size, void* d_ws, size_t ws_size,
                              hipStream_t stream) {
  const float* vid  = (const float*)d_in[0];
  const float* flw  = (const float*)d_in[1];
  const float* g0   = (const float*)d_in[2];
  const float* b0   = (const float*)d_in[3];
  const float* Wq   = (const float*)d_in[4];
  const float* Wk   = (const float*)d_in[5];
  const float* Wv   = (const float*)d_in[6];
  const float* Wo   = (const float*)d_in[7];
  const float* g1   = (const float*)d_in[8];
  const float* b1   = (const float*)d_in[9];
  const float* wr1  = (const float*)d_in[10];
  const float* br1  = (const float*)d_in[11];
  const float* wr2  = (const float*)d_in[12];
  const float* br2  = (const float*)d_in[13];
  float* out = (float*)d_out;

  unsigned short* A  = (unsigned short*)d_ws;
  unsigned short* Bs = A + SLOT_ELEMS;
  unsigned short* Cs = Bs + SLOT_ELEMS;
  bool four = ws_size >= (size_t)4*SLOT_ELEMS*2 + 2*294912;
  unsigned short* D  = four ? (Cs + SLOT_ELEMS) : A;   // q/att/vid1 slot
  unsigned short* wt1 = Cs + SLOT_ELEMS + (four ? SLOT_ELEMS : 0);
  unsigned short* wt2 = wt1 + 147456;
  unsigned short* wm  = Cs + WM_OFF;   // bf16 proj mats in free upper half of Cs (v-fp8 uses lower 8MB)

  k_wprep   <<<832, 256, 0, stream>>>(wr1, wr2, Wq, Wk, Wv, Wo, wt1, wt2, wm);
  k_ln_nchw <<<256, 256, 0, stream>>>(vid, g0, b0, A);
  k_qkv     <<<256, 256, 0, stream>>>(A, wm, D, Bs, Cs);
  k_attn    <<<2048,256, 0, stream>>>(D, Bs, Cs, flw, D);
  k_wo      <<<256, 256, 0, stream>>>(D, wm, vid, D);
  k_ln_rows <<<256, 256, 0, stream>>>(D, g1, b1, Bs);
  k_conv_gelu <<<1024,256,0, stream>>>(Bs, wt1, br1, Cs);
  k_conv_final<<<1024,256,0, stream>>>(Cs, wt2, br2, Bs, D, out);
}

// Round 10
// 434.789 us; speedup vs baseline: 1.0901x; 1.0246x over previous
//
#include <hip/hip_runtime.h>

// ---------- bf16 helpers (bit-level, RNE) ----------
__device__ __forceinline__ float bflo(unsigned int u){ return __builtin_bit_cast(float, (unsigned int)(u<<16)); }
__device__ __forceinline__ float bfhi(unsigned int u){ return __builtin_bit_cast(float, (unsigned int)(u & 0xffff0000u)); }
__device__ __forceinline__ float b2f(unsigned short s){ return __builtin_bit_cast(float, ((unsigned int)s)<<16); }
__device__ __forceinline__ unsigned short f2b(float f){
  unsigned int x = __builtin_bit_cast(unsigned int, f);
  x += 0x7fffu + ((x>>16)&1u);
  return (unsigned short)(x>>16);
}
__device__ __forceinline__ unsigned int packbf(float a, float b){
  return (unsigned int)f2b(a) | ((unsigned int)f2b(b)<<16);
}
__device__ __forceinline__ unsigned short f2h(float f){
  return __builtin_bit_cast(unsigned short, (_Float16)f);
}
__device__ __forceinline__ float dpp_swap1(float s){
  int so = __builtin_amdgcn_mov_dpp(__builtin_bit_cast(int, s), 0xB1, 0xF, 0xF, true); // quad_perm [1,0,3,2]
  return __builtin_bit_cast(float, so);
}
// LDS XOR swizzle: kills the 16-bank aliasing of 256B-stride row reads.
// Involution on byte addresses; applied to BOTH write and read sides.
__device__ __forceinline__ unsigned swz(unsigned b){ return b ^ (((b>>8)&7u)<<4); }

using bf16x8 = __attribute__((ext_vector_type(8))) short;
using f32x4  = __attribute__((ext_vector_type(4))) float;
using f32x2  = __attribute__((ext_vector_type(2))) float;
using h2     = __attribute__((ext_vector_type(2))) _Float16;

__device__ __forceinline__ h2 uh(unsigned int u){ return __builtin_bit_cast(h2, u); }

#define NPOS 65536          // T*H*W
#define SLOT_ELEMS 8388608  // NPOS*128 bf16 elements
#define WM_OFF 6291456      // wm offset (shorts) inside Cs slot (v-fp8 uses first 4194304)

// ---------- K0: conv weights fp32 (O,C,3,3) -> bf16 (tap,O,C);
// projection mats Wq(+scale),Wk,Wv,Wo fp32 -> bf16 [mat][o][c] ----
__global__ __launch_bounds__(256) void k_wprep(const float* __restrict__ w1,
                                               const float* __restrict__ w2,
                                               const float* __restrict__ Wq,
                                               const float* __restrict__ Wk,
                                               const float* __restrict__ Wv,
                                               const float* __restrict__ Wo,
                                               unsigned short* __restrict__ o1,
                                               unsigned short* __restrict__ o2,
                                               unsigned short* __restrict__ wm){
  int idx = blockIdx.x*256 + threadIdx.x;
  if (idx < 147456){
    int o = idx / 1152;
    int rem = idx - o*1152;
    int c = rem / 9;
    int tap = rem - c*9;
    int dsti = tap*16384 + o*128 + c;
    o1[dsti] = f2b(w1[idx]);
    o2[dsti] = f2b(w2[idx]);
  } else if (idx < 212992){
    int idx2 = idx - 147456;
    int mat = idx2 >> 14;
    int ij  = idx2 & 16383;
    // q scale = (1/sqrt(32)) * log2(e) folded into Wq
    float v = (mat==0) ? Wq[ij]*0.2550348613f
            : (mat==1) ? Wk[ij]
            : (mat==2) ? Wv[ij] : Wo[ij];
    wm[idx2] = f2b(v);
  }
}

// ---------- K1: LayerNorm over C, fp32 NCHW input -> (N,C) bf16 ----------
__global__ __launch_bounds__(256) void k_ln_nchw(const float* __restrict__ vid,
                                                 const float* __restrict__ g,
                                                 const float* __restrict__ b,
                                                 unsigned short* __restrict__ xf){
  int n = blockIdx.x*256 + threadIdx.x;
  int t = n >> 14, hw = n & 16383;
  const float* base = vid + (size_t)t*2097152 + hw;
  float s=0.f, ss=0.f;
  #pragma unroll 8
  for (int c=0;c<128;c++){ float v=base[(size_t)c*16384]; s+=v; ss+=v*v; }
  float mu  = s*0.0078125f;
  float var = fmaxf(ss*0.0078125f - mu*mu, 0.f);
  float rs  = rsqrtf(var + 1e-6f);
  unsigned int* op = (unsigned int*)(xf + (size_t)n*128);
  #pragma unroll 4
  for (int c=0;c<128;c+=2){
    float v0=(base[(size_t)c*16384]    -mu)*rs*g[c]  +b[c];
    float v1=(base[(size_t)(c+1)*16384]-mu)*rs*g[c+1]+b[c+1];
    op[c>>1]=packbf(v0,v1);
  }
}

// ---------- K5: LayerNorm over C, (N,C) bf16 row-major input ----------
__global__ __launch_bounds__(256) void k_ln_rows(const unsigned short* __restrict__ x,
                                                 const float* __restrict__ g,
                                                 const float* __restrict__ b,
                                                 unsigned short* __restrict__ y){
  int n = blockIdx.x*256 + threadIdx.x;
  const unsigned int* p = (const unsigned int*)(x + (size_t)n*128);
  float s=0.f, ss=0.f;
  #pragma unroll 8
  for (int j=0;j<64;j++){ unsigned int u=p[j]; float v0=bflo(u),v1=bfhi(u); s+=v0+v1; ss+=v0*v0+v1*v1; }
  float mu  = s*0.0078125f;
  float var = fmaxf(ss*0.0078125f - mu*mu, 0.f);
  float rs  = rsqrtf(var + 1e-6f);
  unsigned int* op=(unsigned int*)(y+(size_t)n*128);
  #pragma unroll 8
  for (int j=0;j<64;j++){
    unsigned int u=p[j];
    float v0=(bflo(u)-mu)*rs*g[2*j]  +b[2*j];
    float v1=(bfhi(u)-mu)*rs*g[2*j+1]+b[2*j+1];
    op[j]=packbf(v0,v1);
  }
}

// ---------- K2: QKV projections. 256 rows/block (4 m-tiles per wave).
// Weights pre-converted bf16 (q pre-scaled), LDS XOR-swizzled.
// q,k -> fp16; v -> fp8 e4m3. Mat order v,k,q (q-store last; may alias x) ----
__global__ __launch_bounds__(256) void k_qkv(const unsigned short* xf,
                                             const unsigned short* __restrict__ wm,
                                             unsigned short* qf,
                                             unsigned short* __restrict__ kfo,
                                             unsigned short* __restrict__ vfo){
  __shared__ unsigned short wlds[16384];
  int wave = threadIdx.x>>6, lane = threadIdx.x&63;
  int m0w = blockIdx.x*256 + wave*64;
  int mrow = lane&15, quad = lane>>4;
  #pragma unroll 1
  for (int mi=0; mi<3; mi++){
    int mat = 2-mi;                       // v, k, q
    __syncthreads();
    { const uint4* src=(const uint4*)(wm + mat*16384);
      #pragma unroll
      for (int i=0;i<8;i++){
        unsigned bb=(threadIdx.x+256*i)*16;
        *(uint4*)((char*)wlds + swz(bb)) = src[threadIdx.x+256*i];
      } }
    __syncthreads();
    #pragma unroll 1
    for (int mt=0; mt<4; mt++){
      int m0 = m0w + mt*16;
      bf16x8 a[4];
      const unsigned short* ap = xf + (size_t)(m0+mrow)*128 + quad*8;
      #pragma unroll
      for (int kc=0;kc<4;kc++) a[kc] = *(const bf16x8*)(ap + kc*32);
      for (int nt=0;nt<8;nt++){
        f32x4 acc = {0.f,0.f,0.f,0.f};
        #pragma unroll
        for (int kc=0;kc<4;kc++){
          bf16x8 bfr = *(const bf16x8*)((const char*)wlds + swz((nt*16+mrow)*256 + kc*64 + quad*16));
          acc = __builtin_amdgcn_mfma_f32_16x16x32_bf16(a[kc], bfr, acc, 0,0,0);
        }
        int col = nt*16+mrow;
        if (mat==2){
          // v: fp8 e4m3, 128 bytes per pixel row
          unsigned char* op8 = (unsigned char*)vfo + (size_t)(m0 + quad*4)*128 + col;
          #pragma unroll
          for (int r=0;r<4;r++){
            int pk = __builtin_amdgcn_cvt_pk_fp8_f32(acc[r], acc[r], 0, false);
            op8[(size_t)r*128] = (unsigned char)(pk & 0xff);
          }
        } else {
          unsigned short* out = (mat==0) ? qf : kfo;
          unsigned short* op = out + (size_t)(m0 + quad*4)*128 + col;
          #pragma unroll
          for (int r=0;r<4;r++) op[(size_t)r*128] = f2h(acc[r]);   // fp16 (q scale in W)
        }
      }
    }
  }
}

// ---------- K3: attention (R5 verbatim — best measured 167 µs).
// 2 threads/pixel-head, 16 ch each; fdot2 QK; exp2f; fp8 V PV;
// cross-row prefetch pipeline. Output bf16 normal order ----
__global__ __launch_bounds__(256) void k_attn(const unsigned short* qf,
                                              const unsigned short* __restrict__ kf,
                                              const unsigned short* __restrict__ vf,
                                              const float* __restrict__ flw,
                                              unsigned short* attf){
  int xcd = blockIdx.x & 7;
  int j   = blockIdx.x >> 3;      // 0..255
  int t       = j >> 6;           // 0..3
  int r       = j & 63;
  int h_local = r >> 2;           // 0..15
  int wq      = r & 3;            // 0..3
  int h = xcd*16 + h_local;
  int w = wq*32 + (threadIdx.x >> 3);
  int head  = (threadIdx.x >> 1) & 3;
  int cpart = threadIdx.x & 1;
  int hw = (h<<7) + w;
  int n  = (t<<14) + hw;
  float fh = flw[t*32768 + hw];
  float fw = flw[t*32768 + 16384 + hw];
  unsigned coff = head*32 + cpart*16;     // this thread's 16-channel slice
  const unsigned char* vf8 = (const unsigned char*)vf;   // fp8 rows, 128B/pixel
  const uint4* qp = (const uint4*)(qf + (size_t)n*128 + coff);
  uint4 q0v = qp[0], q1v = qp[1];
  unsigned qw[8] = {q0v.x,q0v.y,q0v.z,q0v.w,q1v.x,q1v.y,q1v.z,q1v.w};
  float acc[16];
  #pragma unroll
  for (int i=0;i<16;i++) acc[i]=0.f;
  float l = 0.f;

  // ---- per-dt window params (x = dt+1), all precomputed ----
  int rowb0, rowb1, rowb2;     // clamped ti << 14
  int hb0, hb1, hb2;           // h + oh(dt)
  int wm30, wm31, wm32;        // w + ow(dt) - 3
  int w0c0, w0c1, w0c2;        // clamp(wm3)
  {
    int ti;
    ti = t-1; ti = ti<0?0:ti;   rowb0 = ti<<14;
    rowb1 = t<<14;
    ti = t+1; ti = ti>3?3:ti;   rowb2 = ti<<14;
    int oh = (int)rintf(fh*(-1.0f)), ow = (int)rintf(fw*(-1.0f));
    hb0 = h+oh; wm30 = w+ow-3;
    hb1 = h;    wm31 = w-3;
    oh = (int)rintf(fh*(1.0f)); ow = (int)rintf(fw*(1.0f));
    hb2 = h+oh; wm32 = w+ow-3;
    w0c0 = wm30<0?0:(wm30>127?127:wm30);
    w0c1 = wm31<0?0:(wm31>127?127:wm31);
    w0c2 = wm32<0?0:(wm32>127?127:wm32);
  }

  // ---- pipeline prologue: first position (dt=-1, dh=-3, tap 0) ----
  uint4 ka0, ka1, va;
  {
    int hi0 = hb0-3; hi0 = hi0<0?0:(hi0>127?127:hi0);
    unsigned b0 = ((unsigned)(rowb0 + (hi0<<7) + w0c0)<<7) + coff;
    ka0 = ((const uint4*)(kf + b0))[0];
    ka1 = ((const uint4*)(kf + b0))[1];
    va  = *(const uint4*)(vf8 + b0);
  }

  #pragma unroll
  for (int x=0; x<3; x++){
    const int rb_t = (x==0)?rowb0:((x==1)?rowb1:rowb2);
    const int hb   = (x==0)?hb0:((x==1)?hb1:hb2);
    const int wm3  = (x==0)?wm30:((x==1)?wm31:wm32);
    const int w0c  = (x==0)?w0c0:((x==1)?w0c1:w0c2);
    // next-dt first-row params (compile-time selected; unused for x==2)
    const int nrb  = (x==0)?rowb1:rowb2;
    const int nhb  = (x==0)?hb1:hb2;
    const int nw0c = (x==0)?w0c1:w0c2;
    #pragma unroll 1
    for (int dh=-3; dh<=3; dh++){
      int hi = hb+dh; hi = hi<0?0:(hi>127?127:hi);
      int rbase = rb_t + (hi<<7);
      #pragma unroll
      for (int i=0;i<7;i++){
        // ---- compute next prefetch address ----
        unsigned bon;
        if (i<6){
          int wi = wm3+i+1; wi = wi<0?0:(wi>127?127:wi);
          bon = ((unsigned)(rbase + wi)<<7) + coff;
        } else if (dh<3){
          // next row of same dt, tap 0
          int hi2 = hb+dh+1; hi2 = hi2<0?0:(hi2>127?127:hi2);
          bon = ((unsigned)(rb_t + (hi2<<7) + w0c)<<7) + coff;
        } else if (x<2){
          // first row of next dt, tap 0
          int hi2 = nhb-3; hi2 = hi2<0?0:(hi2>127?127:hi2);
          bon = ((unsigned)(nrb + (hi2<<7) + nw0c)<<7) + coff;
        } else {
          bon = coff;     // final iteration: harmless dummy
        }
        uint4 kb0 = ((const uint4*)(kf + bon))[0];
        uint4 kb1 = ((const uint4*)(kf + bon))[1];
        uint4 vb  = *(const uint4*)(vf8 + bon);
        // ---- QK: two dot2 chains of 4 (16 channels in 8 VALU ops) ----
        float s0 = 0.f, s1 = 0.f;
        s0 = __builtin_amdgcn_fdot2(uh(qw[0]), uh(ka0.x), s0, false);
        s0 = __builtin_amdgcn_fdot2(uh(qw[1]), uh(ka0.y), s0, false);
        s0 = __builtin_amdgcn_fdot2(uh(qw[2]), uh(ka0.z), s0, false);
        s0 = __builtin_amdgcn_fdot2(uh(qw[3]), uh(ka0.w), s0, false);
        s1 = __builtin_amdgcn_fdot2(uh(qw[4]), uh(ka1.x), s1, false);
        s1 = __builtin_amdgcn_fdot2(uh(qw[5]), uh(ka1.y), s1, false);
        s1 = __builtin_amdgcn_fdot2(uh(qw[6]), uh(ka1.z), s1, false);
        s1 = __builtin_amdgcn_fdot2(uh(qw[7]), uh(ka1.w), s1, false);
        float s = s0 + s1;
        s += dpp_swap1(s);               // combine the two channel halves
        float e = exp2f(s);              // 2^s == exp(scale*(q.k)), log2e folded in q
        l += e;
        // ---- PV: decode 16 fp8 -> f32 pairs, FMA with e ----
        f32x2 c0 = __builtin_amdgcn_cvt_pk_f32_fp8((int)va.x, false);
        f32x2 c1 = __builtin_amdgcn_cvt_pk_f32_fp8((int)va.x, true);
        f32x2 c2 = __builtin_amdgcn_cvt_pk_f32_fp8((int)va.y, false);
        f32x2 c3 = __builtin_amdgcn_cvt_pk_f32_fp8((int)va.y, true);
        f32x2 c4 = __builtin_amdgcn_cvt_pk_f32_fp8((int)va.z, false);
        f32x2 c5 = __builtin_amdgcn_cvt_pk_f32_fp8((int)va.z, true);
        f32x2 c6 = __builtin_amdgcn_cvt_pk_f32_fp8((int)va.w, false);
        f32x2 c7 = __builtin_amdgcn_cvt_pk_f32_fp8((int)va.w, true);
        acc[0]  += e*c0.x; acc[1]  += e*c0.y;
        acc[2]  += e*c1.x; acc[3]  += e*c1.y;
        acc[4]  += e*c2.x; acc[5]  += e*c2.y;
        acc[6]  += e*c3.x; acc[7]  += e*c3.y;
        acc[8]  += e*c4.x; acc[9]  += e*c4.y;
        acc[10] += e*c5.x; acc[11] += e*c5.y;
        acc[12] += e*c6.x; acc[13] += e*c6.y;
        acc[14] += e*c7.x; acc[15] += e*c7.y;
        ka0=kb0; ka1=kb1; va=vb;
      }
    }
  }
  float inv = 1.f/l;
  unsigned int* op = (unsigned int*)(attf + (size_t)n*128 + coff);
  #pragma unroll
  for (int i=0;i<8;i++) op[i]=packbf(acc[2*i]*inv, acc[2*i+1]*inv);
}

// ---------- K4: Wo projection + residual. 256 rows/block, bf16 Wo from wm,
// LDS XOR-swizzled. vid1 may alias attf ----
__global__ __launch_bounds__(256) void k_wo(const unsigned short* attf,
                                            const unsigned short* __restrict__ wm,
                                            const float* __restrict__ vid,
                                            unsigned short* vid1){
  __shared__ unsigned short wlds[16384];
  int wave = threadIdx.x>>6, lane = threadIdx.x&63;
  int m0w = blockIdx.x*256 + wave*64;
  int mrow = lane&15, quad = lane>>4;
  { const uint4* src=(const uint4*)(wm + 49152);
    #pragma unroll
    for (int i=0;i<8;i++){
      unsigned bb=(threadIdx.x+256*i)*16;
      *(uint4*)((char*)wlds + swz(bb)) = src[threadIdx.x+256*i];
    } }
  __syncthreads();
  #pragma unroll 1
  for (int mt=0; mt<4; mt++){
    int m0 = m0w + mt*16;
    bf16x8 a[4];
    const unsigned short* ap = attf + (size_t)(m0+mrow)*128 + quad*8;
    #pragma unroll
    for (int kc=0;kc<4;kc++) a[kc] = *(const bf16x8*)(ap + kc*32);
    for (int nt=0;nt<8;nt++){
      f32x4 acc={0.f,0.f,0.f,0.f};
      #pragma unroll
      for (int kc=0;kc<4;kc++){
        bf16x8 bfr = *(const bf16x8*)((const char*)wlds + swz((nt*16+mrow)*256 + kc*64 + quad*16));
        acc = __builtin_amdgcn_mfma_f32_16x16x32_bf16(a[kc], bfr, acc, 0,0,0);
      }
      int col = nt*16+mrow;
      #pragma unroll
      for (int r=0;r<4;r++){
        int nrow = m0 + quad*4 + r;
        int tt = nrow>>14, hww = nrow&16383;
        float resid = vid[(size_t)tt*2097152 + (size_t)col*16384 + hww];
        vid1[(size_t)nrow*128 + col] = f2b(resid + acc[r]);
      }
    }
  }
}

// ---------- K6/K7 shared conv core: chalf-split + LDS-staged input rows ----------
// Block = (frame, row h, col-half). M=128 (full row), 64 out channels.
// Input row (128 px x 128 ch = 32KB) staged in inlds ONCE PER ky and read by
// all 3 kx taps via swizzled ds_read_b128 (was: 3x redundant global gathers
// with latency exposed inside every barrier-fenced tap). Next row register-
// prefetched (8 uint4/thread) during kx==2 compute, written at tap boundary.
// Weights: 16KB wlds, reg-prefetch next tap (unchanged). 48KB LDS total.
// Accumulation order identical to R7/R9 -> bit-identical results.
#define CONV_PROLOG \
  __shared__ unsigned short wlds[8192]; \
  __shared__ unsigned short inlds[16384]; \
  int wv = threadIdx.x>>6, lane = threadIdx.x&63; \
  int mrow = lane&15, quad = lane>>4; \
  int chalf = blockIdx.x & 1; \
  int h = (blockIdx.x>>1) & 127; \
  int frame = blockIdx.x>>8; \
  size_t nf = (size_t)frame*16384; \
  f32x4 accA[4], accB[4]; \
  _Pragma("unroll") \
  for (int i=0;i<4;i++){ accA[i]=(f32x4){0.f,0.f,0.f,0.f}; accB[i]=(f32x4){0.f,0.f,0.f,0.f}; } \
  { const uint4* sp=(const uint4*)(wtap + chalf*8192); \
    uint4 s0=sp[threadIdx.x], s1=sp[threadIdx.x+256], s2=sp[threadIdx.x+512], s3=sp[threadIdx.x+768]; \
    unsigned b0=(unsigned)threadIdx.x*16; \
    *(uint4*)((char*)wlds + swz(b0))         = s0; \
    *(uint4*)((char*)wlds + swz(b0+4096u))   = s1; \
    *(uint4*)((char*)wlds + swz(b0+8192u))   = s2; \
    *(uint4*)((char*)wlds + swz(b0+12288u))  = s3; \
    if (h>=1){ const uint4* ip=(const uint4*)(src + (nf + (size_t)(h-1)*128)*128); \
      _Pragma("unroll") \
      for (int j2=0;j2<8;j2++) \
        *(uint4*)((char*)inlds + swz((unsigned)(threadIdx.x+256*j2)*16)) = ip[threadIdx.x+256*j2]; } } \
  __syncthreads(); \
  _Pragma("unroll 1") \
  for (int ky=0; ky<3; ky++){ \
    int h2c = h+ky-1; \
    bool vld = (unsigned)h2c<128u; \
    _Pragma("unroll 1") \
    for (int kx=0; kx<3; kx++){ \
      int tap = ky*3+kx; \
      uint4 s0,s1,s2,s3; \
      if (tap<8){ const uint4* sp=(const uint4*)(wtap + (size_t)(tap+1)*16384 + chalf*8192); \
        s0=sp[threadIdx.x]; s1=sp[threadIdx.x+256]; s2=sp[threadIdx.x+512]; s3=sp[threadIdx.x+768]; } \
      uint4 tr[8]; \
      bool stg = (kx==2) && (ky<2) && (h+ky<128); \
      if (stg){ const uint4* ip=(const uint4*)(src + (nf + (size_t)(h+ky)*128)*128); \
        _Pragma("unroll") \
        for (int j2=0;j2<8;j2++) tr[j2]=ip[threadIdx.x+256*j2]; } \
      if (vld){ \
        int wA = wv*32 + mrow + kx - 1;            /* [-1,112] */ \
        int wAc = wA < 0 ? 0 : wA; \
        int wB = wA + 16;                          /* [15,128] */ \
        int wBc = wB > 127 ? 127 : wB; \
        bf16x8 aA[4], aB[4]; \
        _Pragma("unroll") \
        for (int kc=0;kc<4;kc++){ \
          aA[kc]=*(const bf16x8*)((const char*)inlds + swz((unsigned)(wAc*256 + kc*64 + quad*16))); \
          aB[kc]=*(const bf16x8*)((const char*)inlds + swz((unsigned)(wBc*256 + kc*64 + quad*16))); } \
        if (kx==0 && wv==0 && mrow==0){ _Pragma("unroll") for (int kc=0;kc<4;kc++) aA[kc]=(bf16x8){0,0,0,0,0,0,0,0}; } \
        if (kx==2 && wv==3 && mrow==15){ _Pragma("unroll") for (int kc=0;kc<4;kc++) aB[kc]=(bf16x8){0,0,0,0,0,0,0,0}; } \
        _Pragma("unroll") \
        for (int nt=0;nt<4;nt++){ \
          _Pragma("unroll") \
          for (int kc=0;kc<4;kc++){ \
            bf16x8 bfr=*(const bf16x8*)((const char*)wlds + swz((nt*16+mrow)*256 + kc*64 + quad*16)); \
            accA[nt]=__builtin_amdgcn_mfma_f32_16x16x32_bf16(aA[kc],bfr,accA[nt],0,0,0); \
            accB[nt]=__builtin_amdgcn_mfma_f32_16x16x32_bf16(aB[kc],bfr,accB[nt],0,0,0); \
          } \
        } \
      } \
      __syncthreads(); \
      if (tap<8){ unsigned b0=(unsigned)threadIdx.x*16; \
        *(uint4*)((char*)wlds + swz(b0))         = s0; \
        *(uint4*)((char*)wlds + swz(b0+4096u))   = s1; \
        *(uint4*)((char*)wlds + swz(b0+8192u))   = s2; \
        *(uint4*)((char*)wlds + swz(b0+12288u))  = s3; } \
      if (stg){ \
        _Pragma("unroll") \
        for (int j2=0;j2<8;j2++) \
          *(uint4*)((char*)inlds + swz((unsigned)(threadIdx.x+256*j2)*16)) = tr[j2]; } \
      if (tap<8) __syncthreads(); \
    } \
  }

// ---------- K6: 3x3 conv + bias + tanh-GELU, (N,C) bf16 out ----------
__global__ __launch_bounds__(256) void k_conv_gelu(const unsigned short* __restrict__ src,
                                                   const unsigned short* __restrict__ wtap,
                                                   const float* __restrict__ bias,
                                                   unsigned short* __restrict__ dst){
  CONV_PROLOG
  #pragma unroll
  for (int nt=0;nt<4;nt++){
    int col = chalf*64 + nt*16 + mrow;
    float bb = bias[col];
    #pragma unroll
    for (int r=0;r<4;r++){
      int pA = h*128 + wv*32 + quad*4 + r;
      float xA = accA[nt][r]+bb;
      float zA = 0.7978845608028654f*(xA+0.044715f*xA*xA*xA);
      dst[(nf+(size_t)pA)*128+col] = f2b(xA * __builtin_amdgcn_rcpf(1.f + __expf(-2.f*zA)));
      float xB = accB[nt][r]+bb;
      float zB = 0.7978845608028654f*(xB+0.044715f*xB*xB*xB);
      dst[(nf+(size_t)(pA+16))*128+col] = f2b(xB * __builtin_amdgcn_rcpf(1.f + __expf(-2.f*zB)));
    }
  }
}

// ---------- K7: 3x3 conv + bias + (vid1 + yb + r) -> d_out fp32 NCHW ----------
__global__ __launch_bounds__(256) void k_conv_final(const unsigned short* __restrict__ src,
                                                    const unsigned short* __restrict__ wtap,
                                                    const float* __restrict__ bias,
                                                    const unsigned short* __restrict__ yb,
                                                    const unsigned short* __restrict__ vid1,
                                                    float* __restrict__ out){
  CONV_PROLOG
  #pragma unroll
  for (int nt=0;nt<4;nt++){
    int col = chalf*64 + nt*16 + mrow;
    float bb = bias[col];
    #pragma unroll
    for (int r=0;r<4;r++){
      int pA = h*128 + wv*32 + quad*4 + r;
      size_t rowA = nf+(size_t)pA, rowB = rowA+16;
      float xA = accA[nt][r]+bb;
      out[(size_t)frame*2097152 + (size_t)col*16384 + pA] =
        b2f(vid1[rowA*128+col]) + b2f(yb[rowA*128+col]) + xA;
      float xB = accB[nt][r]+bb;
      out[(size_t)frame*2097152 + (size_t)col*16384 + pA + 16] =
        b2f(vid1[rowB*128+col]) + b2f(yb[rowB*128+col]) + xB;
    }
  }
}

extern "C" void kernel_launch(void* const* d_in, const int* in_sizes, int n_in,
                              void* d_out, int out_size, void* d_ws, size_t ws_size,
                              hipStream_t stream) {
  const float* vid  = (const float*)d_in[0];
  const float* flw  = (const float*)d_in[1];
  const float* g0   = (const float*)d_in[2];
  const float* b0   = (const float*)d_in[3];
  const float* Wq   = (const float*)d_in[4];
  const float* Wk   = (const float*)d_in[5];
  const float* Wv   = (const float*)d_in[6];
  const float* Wo   = (const float*)d_in[7];
  const float* g1   = (const float*)d_in[8];
  const float* b1   = (const float*)d_in[9];
  const float* wr1  = (const float*)d_in[10];
  const float* br1  = (const float*)d_in[11];
  const float* wr2  = (const float*)d_in[12];
  const float* br2  = (const float*)d_in[13];
  float* out = (float*)d_out;

  unsigned short* A  = (unsigned short*)d_ws;
  unsigned short* Bs = A + SLOT_ELEMS;
  unsigned short* Cs = Bs + SLOT_ELEMS;
  bool four = ws_size >= (size_t)4*SLOT_ELEMS*2 + 2*294912;
  unsigned short* D  = four ? (Cs + SLOT_ELEMS) : A;   // q/att/vid1 slot
  unsigned short* wt1 = Cs + SLOT_ELEMS + (four ? SLOT_ELEMS : 0);
  unsigned short* wt2 = wt1 + 147456;
  unsigned short* wm  = Cs + WM_OFF;   // bf16 proj mats in free upper half of Cs (v-fp8 uses lower 8MB)

  k_wprep   <<<832, 256, 0, stream>>>(wr1, wr2, Wq, Wk, Wv, Wo, wt1, wt2, wm);
  k_ln_nchw <<<256, 256, 0, stream>>>(vid, g0, b0, A);
  k_qkv     <<<256, 256, 0, stream>>>(A, wm, D, Bs, Cs);
  k_attn    <<<2048,256, 0, stream>>>(D, Bs, Cs, flw, D);
  k_wo      <<<256, 256, 0, stream>>>(D, wm, vid, D);
  k_ln_rows <<<256, 256, 0, stream>>>(D, g1, b1, Bs);
  k_conv_gelu <<<1024,256,0, stream>>>(Bs, wt1, br1, Cs);
  k_conv_final<<<1024,256,0, stream>>>(Cs, wt2, br2, Bs, D, out);
}

// Round 11
// 429.187 us; speedup vs baseline: 1.1044x; 1.0131x over previous
//
#include <hip/hip_runtime.h>

// ---------- bf16 helpers (bit-level, RNE) ----------
__device__ __forceinline__ float bflo(unsigned int u){ return __builtin_bit_cast(float, (unsigned int)(u<<16)); }
__device__ __forceinline__ float bfhi(unsigned int u){ return __builtin_bit_cast(float, (unsigned int)(u & 0xffff0000u)); }
__device__ __forceinline__ float b2f(unsigned short s){ return __builtin_bit_cast(float, ((unsigned int)s)<<16); }
__device__ __forceinline__ unsigned short f2b(float f){
  unsigned int x = __builtin_bit_cast(unsigned int, f);
  x += 0x7fffu + ((x>>16)&1u);
  return (unsigned short)(x>>16);
}
__device__ __forceinline__ unsigned int packbf(float a, float b){
  return (unsigned int)f2b(a) | ((unsigned int)f2b(b)<<16);
}
__device__ __forceinline__ unsigned short f2h(float f){
  return __builtin_bit_cast(unsigned short, (_Float16)f);
}
__device__ __forceinline__ float dpp_swap1(float s){
  int so = __builtin_amdgcn_mov_dpp(__builtin_bit_cast(int, s), 0xB1, 0xF, 0xF, true); // quad_perm [1,0,3,2]
  return __builtin_bit_cast(float, so);
}
// LDS XOR swizzle: kills the 16-bank aliasing of 256B-stride row reads.
// Involution on byte addresses; applied to BOTH write and read sides.
__device__ __forceinline__ unsigned swz(unsigned b){ return b ^ (((b>>8)&7u)<<4); }

using bf16x8 = __attribute__((ext_vector_type(8))) short;
using f32x4  = __attribute__((ext_vector_type(4))) float;
using f32x2  = __attribute__((ext_vector_type(2))) float;
using h2     = __attribute__((ext_vector_type(2))) _Float16;

__device__ __forceinline__ h2 uh(unsigned int u){ return __builtin_bit_cast(h2, u); }

#define NPOS 65536          // T*H*W
#define SLOT_ELEMS 8388608  // NPOS*128 bf16 elements
#define WM_OFF 6291456      // wm offset (shorts) inside Cs slot (v-fp8 uses first 4194304)

// ---------- K0: conv weights fp32 (O,C,3,3) -> bf16 (tap,O,C);
// projection mats Wq(+scale),Wk,Wv,Wo fp32 -> bf16 [mat][o][c] ----
__global__ __launch_bounds__(256) void k_wprep(const float* __restrict__ w1,
                                               const float* __restrict__ w2,
                                               const float* __restrict__ Wq,
                                               const float* __restrict__ Wk,
                                               const float* __restrict__ Wv,
                                               const float* __restrict__ Wo,
                                               unsigned short* __restrict__ o1,
                                               unsigned short* __restrict__ o2,
                                               unsigned short* __restrict__ wm){
  int idx = blockIdx.x*256 + threadIdx.x;
  if (idx < 147456){
    int o = idx / 1152;
    int rem = idx - o*1152;
    int c = rem / 9;
    int tap = rem - c*9;
    int dsti = tap*16384 + o*128 + c;
    o1[dsti] = f2b(w1[idx]);
    o2[dsti] = f2b(w2[idx]);
  } else if (idx < 212992){
    int idx2 = idx - 147456;
    int mat = idx2 >> 14;
    int ij  = idx2 & 16383;
    // q scale = (1/sqrt(32)) * log2(e) folded into Wq
    float v = (mat==0) ? Wq[ij]*0.2550348613f
            : (mat==1) ? Wk[ij]
            : (mat==2) ? Wv[ij] : Wo[ij];
    wm[idx2] = f2b(v);
  }
}

// ---------- K1: LayerNorm over C, fp32 NCHW input -> (N,C) bf16 ----------
__global__ __launch_bounds__(256) void k_ln_nchw(const float* __restrict__ vid,
                                                 const float* __restrict__ g,
                                                 const float* __restrict__ b,
                                                 unsigned short* __restrict__ xf){
  int n = blockIdx.x*256 + threadIdx.x;
  int t = n >> 14, hw = n & 16383;
  const float* base = vid + (size_t)t*2097152 + hw;
  float s=0.f, ss=0.f;
  #pragma unroll 8
  for (int c=0;c<128;c++){ float v=base[(size_t)c*16384]; s+=v; ss+=v*v; }
  float mu  = s*0.0078125f;
  float var = fmaxf(ss*0.0078125f - mu*mu, 0.f);
  float rs  = rsqrtf(var + 1e-6f);
  unsigned int* op = (unsigned int*)(xf + (size_t)n*128);
  #pragma unroll 4
  for (int c=0;c<128;c+=2){
    float v0=(base[(size_t)c*16384]    -mu)*rs*g[c]  +b[c];
    float v1=(base[(size_t)(c+1)*16384]-mu)*rs*g[c+1]+b[c+1];
    op[c>>1]=packbf(v0,v1);
  }
}

// ---------- K2: QKV projections. 128 rows/block, 512 blocks (2 blocks/CU TLP).
// Weights pre-converted bf16 (q pre-scaled), LDS XOR-swizzled.
// q,k -> fp16; v -> fp8 e4m3. Mat order v,k,q (q-store last; may alias x) ----
__global__ __launch_bounds__(256) void k_qkv(const unsigned short* xf,
                                             const unsigned short* __restrict__ wm,
                                             unsigned short* qf,
                                             unsigned short* __restrict__ kfo,
                                             unsigned short* __restrict__ vfo){
  __shared__ unsigned short wlds[16384];
  int wave = threadIdx.x>>6, lane = threadIdx.x&63;
  int m0w = blockIdx.x*128 + wave*32;
  int mrow = lane&15, quad = lane>>4;
  #pragma unroll 1
  for (int mi=0; mi<3; mi++){
    int mat = 2-mi;                       // v, k, q
    __syncthreads();
    { const uint4* src=(const uint4*)(wm + mat*16384);
      #pragma unroll
      for (int i=0;i<8;i++){
        unsigned bb=(threadIdx.x+256*i)*16;
        *(uint4*)((char*)wlds + swz(bb)) = src[threadIdx.x+256*i];
      } }
    __syncthreads();
    #pragma unroll 1
    for (int mt=0; mt<2; mt++){
      int m0 = m0w + mt*16;
      bf16x8 a[4];
      const unsigned short* ap = xf + (size_t)(m0+mrow)*128 + quad*8;
      #pragma unroll
      for (int kc=0;kc<4;kc++) a[kc] = *(const bf16x8*)(ap + kc*32);
      for (int nt=0;nt<8;nt++){
        f32x4 acc = {0.f,0.f,0.f,0.f};
        #pragma unroll
        for (int kc=0;kc<4;kc++){
          bf16x8 bfr = *(const bf16x8*)((const char*)wlds + swz((nt*16+mrow)*256 + kc*64 + quad*16));
          acc = __builtin_amdgcn_mfma_f32_16x16x32_bf16(a[kc], bfr, acc, 0,0,0);
        }
        int col = nt*16+mrow;
        if (mat==2){
          // v: fp8 e4m3, 128 bytes per pixel row
          unsigned char* op8 = (unsigned char*)vfo + (size_t)(m0 + quad*4)*128 + col;
          #pragma unroll
          for (int r=0;r<4;r++){
            int pk = __builtin_amdgcn_cvt_pk_fp8_f32(acc[r], acc[r], 0, false);
            op8[(size_t)r*128] = (unsigned char)(pk & 0xff);
          }
        } else {
          unsigned short* out = (mat==0) ? qf : kfo;
          unsigned short* op = out + (size_t)(m0 + quad*4)*128 + col;
          #pragma unroll
          for (int r=0;r<4;r++) op[(size_t)r*128] = f2h(acc[r]);   // fp16 (q scale in W)
        }
      }
    }
  }
}

// ---------- K3: attention (R5 verbatim — best measured 167 µs).
// 2 threads/pixel-head, 16 ch each; fdot2 QK; exp2f; fp8 V PV;
// cross-row prefetch pipeline. Output bf16 normal order ----
__global__ __launch_bounds__(256) void k_attn(const unsigned short* qf,
                                              const unsigned short* __restrict__ kf,
                                              const unsigned short* __restrict__ vf,
                                              const float* __restrict__ flw,
                                              unsigned short* attf){
  int xcd = blockIdx.x & 7;
  int j   = blockIdx.x >> 3;      // 0..255
  int t       = j >> 6;           // 0..3
  int r       = j & 63;
  int h_local = r >> 2;           // 0..15
  int wq      = r & 3;            // 0..3
  int h = xcd*16 + h_local;
  int w = wq*32 + (threadIdx.x >> 3);
  int head  = (threadIdx.x >> 1) & 3;
  int cpart = threadIdx.x & 1;
  int hw = (h<<7) + w;
  int n  = (t<<14) + hw;
  float fh = flw[t*32768 + hw];
  float fw = flw[t*32768 + 16384 + hw];
  unsigned coff = head*32 + cpart*16;     // this thread's 16-channel slice
  const unsigned char* vf8 = (const unsigned char*)vf;   // fp8 rows, 128B/pixel
  const uint4* qp = (const uint4*)(qf + (size_t)n*128 + coff);
  uint4 q0v = qp[0], q1v = qp[1];
  unsigned qw[8] = {q0v.x,q0v.y,q0v.z,q0v.w,q1v.x,q1v.y,q1v.z,q1v.w};
  float acc[16];
  #pragma unroll
  for (int i=0;i<16;i++) acc[i]=0.f;
  float l = 0.f;

  // ---- per-dt window params (x = dt+1), all precomputed ----
  int rowb0, rowb1, rowb2;     // clamped ti << 14
  int hb0, hb1, hb2;           // h + oh(dt)
  int wm30, wm31, wm32;        // w + ow(dt) - 3
  int w0c0, w0c1, w0c2;        // clamp(wm3)
  {
    int ti;
    ti = t-1; ti = ti<0?0:ti;   rowb0 = ti<<14;
    rowb1 = t<<14;
    ti = t+1; ti = ti>3?3:ti;   rowb2 = ti<<14;
    int oh = (int)rintf(fh*(-1.0f)), ow = (int)rintf(fw*(-1.0f));
    hb0 = h+oh; wm30 = w+ow-3;
    hb1 = h;    wm31 = w-3;
    oh = (int)rintf(fh*(1.0f)); ow = (int)rintf(fw*(1.0f));
    hb2 = h+oh; wm32 = w+ow-3;
    w0c0 = wm30<0?0:(wm30>127?127:wm30);
    w0c1 = wm31<0?0:(wm31>127?127:wm31);
    w0c2 = wm32<0?0:(wm32>127?127:wm32);
  }

  // ---- pipeline prologue: first position (dt=-1, dh=-3, tap 0) ----
  uint4 ka0, ka1, va;
  {
    int hi0 = hb0-3; hi0 = hi0<0?0:(hi0>127?127:hi0);
    unsigned b0 = ((unsigned)(rowb0 + (hi0<<7) + w0c0)<<7) + coff;
    ka0 = ((const uint4*)(kf + b0))[0];
    ka1 = ((const uint4*)(kf + b0))[1];
    va  = *(const uint4*)(vf8 + b0);
  }

  #pragma unroll
  for (int x=0; x<3; x++){
    const int rb_t = (x==0)?rowb0:((x==1)?rowb1:rowb2);
    const int hb   = (x==0)?hb0:((x==1)?hb1:hb2);
    const int wm3  = (x==0)?wm30:((x==1)?wm31:wm32);
    const int w0c  = (x==0)?w0c0:((x==1)?w0c1:w0c2);
    // next-dt first-row params (compile-time selected; unused for x==2)
    const int nrb  = (x==0)?rowb1:rowb2;
    const int nhb  = (x==0)?hb1:hb2;
    const int nw0c = (x==0)?w0c1:w0c2;
    #pragma unroll 1
    for (int dh=-3; dh<=3; dh++){
      int hi = hb+dh; hi = hi<0?0:(hi>127?127:hi);
      int rbase = rb_t + (hi<<7);
      #pragma unroll
      for (int i=0;i<7;i++){
        // ---- compute next prefetch address ----
        unsigned bon;
        if (i<6){
          int wi = wm3+i+1; wi = wi<0?0:(wi>127?127:wi);
          bon = ((unsigned)(rbase + wi)<<7) + coff;
        } else if (dh<3){
          // next row of same dt, tap 0
          int hi2 = hb+dh+1; hi2 = hi2<0?0:(hi2>127?127:hi2);
          bon = ((unsigned)(rb_t + (hi2<<7) + w0c)<<7) + coff;
        } else if (x<2){
          // first row of next dt, tap 0
          int hi2 = nhb-3; hi2 = hi2<0?0:(hi2>127?127:hi2);
          bon = ((unsigned)(nrb + (hi2<<7) + nw0c)<<7) + coff;
        } else {
          bon = coff;     // final iteration: harmless dummy
        }
        uint4 kb0 = ((const uint4*)(kf + bon))[0];
        uint4 kb1 = ((const uint4*)(kf + bon))[1];
        uint4 vb  = *(const uint4*)(vf8 + bon);
        // ---- QK: two dot2 chains of 4 (16 channels in 8 VALU ops) ----
        float s0 = 0.f, s1 = 0.f;
        s0 = __builtin_amdgcn_fdot2(uh(qw[0]), uh(ka0.x), s0, false);
        s0 = __builtin_amdgcn_fdot2(uh(qw[1]), uh(ka0.y), s0, false);
        s0 = __builtin_amdgcn_fdot2(uh(qw[2]), uh(ka0.z), s0, false);
        s0 = __builtin_amdgcn_fdot2(uh(qw[3]), uh(ka0.w), s0, false);
        s1 = __builtin_amdgcn_fdot2(uh(qw[4]), uh(ka1.x), s1, false);
        s1 = __builtin_amdgcn_fdot2(uh(qw[5]), uh(ka1.y), s1, false);
        s1 = __builtin_amdgcn_fdot2(uh(qw[6]), uh(ka1.z), s1, false);
        s1 = __builtin_amdgcn_fdot2(uh(qw[7]), uh(ka1.w), s1, false);
        float s = s0 + s1;
        s += dpp_swap1(s);               // combine the two channel halves
        float e = exp2f(s);              // 2^s == exp(scale*(q.k)), log2e folded in q
        l += e;
        // ---- PV: decode 16 fp8 -> f32 pairs, FMA with e ----
        f32x2 c0 = __builtin_amdgcn_cvt_pk_f32_fp8((int)va.x, false);
        f32x2 c1 = __builtin_amdgcn_cvt_pk_f32_fp8((int)va.x, true);
        f32x2 c2 = __builtin_amdgcn_cvt_pk_f32_fp8((int)va.y, false);
        f32x2 c3 = __builtin_amdgcn_cvt_pk_f32_fp8((int)va.y, true);
        f32x2 c4 = __builtin_amdgcn_cvt_pk_f32_fp8((int)va.z, false);
        f32x2 c5 = __builtin_amdgcn_cvt_pk_f32_fp8((int)va.z, true);
        f32x2 c6 = __builtin_amdgcn_cvt_pk_f32_fp8((int)va.w, false);
        f32x2 c7 = __builtin_amdgcn_cvt_pk_f32_fp8((int)va.w, true);
        acc[0]  += e*c0.x; acc[1]  += e*c0.y;
        acc[2]  += e*c1.x; acc[3]  += e*c1.y;
        acc[4]  += e*c2.x; acc[5]  += e*c2.y;
        acc[6]  += e*c3.x; acc[7]  += e*c3.y;
        acc[8]  += e*c4.x; acc[9]  += e*c4.y;
        acc[10] += e*c5.x; acc[11] += e*c5.y;
        acc[12] += e*c6.x; acc[13] += e*c6.y;
        acc[14] += e*c7.x; acc[15] += e*c7.y;
        ka0=kb0; ka1=kb1; va=vb;
      }
    }
  }
  float inv = 1.f/l;
  unsigned int* op = (unsigned int*)(attf + (size_t)n*128 + coff);
  #pragma unroll
  for (int i=0;i<8;i++) op[i]=packbf(acc[2*i]*inv, acc[2*i+1]*inv);
}

// ---------- K4: Wo projection + residual + FUSED LayerNorm epilogue.
// 256 rows/block, bf16 Wo from wm (LDS XOR-swizzled).
// Each output row is distributed across the 16 mrow-lanes of a quad
// (8 nt values/lane) -> 4-step shfl_xor gives row mean/var in-register.
// Writes vid1 = bf16(vid + attn@Wo) and yb = bf16(LN(vid1_f32)).
// vid1 may alias attf (a[] reads precede stores per m-tile) ----
__global__ __launch_bounds__(256) void k_wo(const unsigned short* attf,
                                            const unsigned short* __restrict__ wm,
                                            const float* __restrict__ vid,
                                            const float* __restrict__ g1,
                                            const float* __restrict__ b1,
                                            unsigned short* vid1,
                                            unsigned short* __restrict__ yb){
  __shared__ unsigned short wlds[16384];
  int wave = threadIdx.x>>6, lane = threadIdx.x&63;
  int m0w = blockIdx.x*256 + wave*64;
  int mrow = lane&15, quad = lane>>4;
  { const uint4* src=(const uint4*)(wm + 49152);
    #pragma unroll
    for (int i=0;i<8;i++){
      unsigned bb=(threadIdx.x+256*i)*16;
      *(uint4*)((char*)wlds + swz(bb)) = src[threadIdx.x+256*i];
    } }
  __syncthreads();
  #pragma unroll 1
  for (int mt=0; mt<4; mt++){
    int m0 = m0w + mt*16;
    bf16x8 a[4];
    const unsigned short* ap = attf + (size_t)(m0+mrow)*128 + quad*8;
    #pragma unroll
    for (int kc=0;kc<4;kc++) a[kc] = *(const bf16x8*)(ap + kc*32);
    f32x4 acc8[8];
    #pragma unroll
    for (int nt=0;nt<8;nt++){
      f32x4 acc={0.f,0.f,0.f,0.f};
      #pragma unroll
      for (int kc=0;kc<4;kc++){
        bf16x8 bfr = *(const bf16x8*)((const char*)wlds + swz((nt*16+mrow)*256 + kc*64 + quad*16));
        acc = __builtin_amdgcn_mfma_f32_16x16x32_bf16(a[kc], bfr, acc, 0,0,0);
      }
      acc8[nt]=acc;
    }
    #pragma unroll
    for (int r=0;r<4;r++){
      int nrow = m0 + quad*4 + r;
      int tt = nrow>>14, hww = nrow&16383;
      float v0,v1,v2,v3,v4,v5,v6,v7;
      float s=0.f, ss=0.f;
      v0 = vid[(size_t)tt*2097152 + (size_t)(0*16+mrow)*16384 + hww] + acc8[0][r];
      v1 = vid[(size_t)tt*2097152 + (size_t)(1*16+mrow)*16384 + hww] + acc8[1][r];
      v2 = vid[(size_t)tt*2097152 + (size_t)(2*16+mrow)*16384 + hww] + acc8[2][r];
      v3 = vid[(size_t)tt*2097152 + (size_t)(3*16+mrow)*16384 + hww] + acc8[3][r];
      v4 = vid[(size_t)tt*2097152 + (size_t)(4*16+mrow)*16384 + hww] + acc8[4][r];
      v5 = vid[(size_t)tt*2097152 + (size_t)(5*16+mrow)*16384 + hww] + acc8[5][r];
      v6 = vid[(size_t)tt*2097152 + (size_t)(6*16+mrow)*16384 + hww] + acc8[6][r];
      v7 = vid[(size_t)tt*2097152 + (size_t)(7*16+mrow)*16384 + hww] + acc8[7][r];
      s  = ((v0+v1)+(v2+v3)) + ((v4+v5)+(v6+v7));
      ss = ((v0*v0+v1*v1)+(v2*v2+v3*v3)) + ((v4*v4+v5*v5)+(v6*v6+v7*v7));
      #pragma unroll
      for (int m=1;m<16;m<<=1){ s += __shfl_xor(s,m,64); ss += __shfl_xor(ss,m,64); }
      float mu  = s*0.0078125f;
      float var = fmaxf(ss*0.0078125f - mu*mu, 0.f);
      float rs  = rsqrtf(var + 1e-6f);
      float vv[8] = {v0,v1,v2,v3,v4,v5,v6,v7};
      #pragma unroll
      for (int nt=0;nt<8;nt++){
        int col = nt*16+mrow;
        vid1[(size_t)nrow*128 + col] = f2b(vv[nt]);
        yb[(size_t)nrow*128 + col]   = f2b((vv[nt]-mu)*rs*g1[col] + b1[col]);
      }
    }
  }
}

// ---------- K6/K7 shared conv core: chalf-split + LDS-staged input rows
// + XCD-chunk block swizzle (h-neighbors & chalf-pairs share an XCD L2).
// Block = (frame, row h, col-half). M=128 (full row), 64 out channels.
// Input row (32KB) staged in inlds once per ky, read by all 3 kx taps via
// swizzled ds_read_b128; next row register-prefetched during kx==2 compute.
// Weights: 16KB wlds, reg-prefetch next tap. 48KB LDS total.
#define CONV_PROLOG \
  __shared__ unsigned short wlds[8192]; \
  __shared__ unsigned short inlds[16384]; \
  int wv = threadIdx.x>>6, lane = threadIdx.x&63; \
  int mrow = lane&15, quad = lane>>4; \
  int wg = (int)((blockIdx.x&7)*128 + (blockIdx.x>>3));   /* XCD chunk swizzle, 1024%8==0 */ \
  int chalf = wg & 1; \
  int h = (wg>>1) & 127; \
  int frame = wg>>8; \
  size_t nf = (size_t)frame*16384; \
  f32x4 accA[4], accB[4]; \
  _Pragma("unroll") \
  for (int i=0;i<4;i++){ accA[i]=(f32x4){0.f,0.f,0.f,0.f}; accB[i]=(f32x4){0.f,0.f,0.f,0.f}; } \
  { const uint4* sp=(const uint4*)(wtap + chalf*8192); \
    uint4 s0=sp[threadIdx.x], s1=sp[threadIdx.x+256], s2=sp[threadIdx.x+512], s3=sp[threadIdx.x+768]; \
    unsigned b0=(unsigned)threadIdx.x*16; \
    *(uint4*)((char*)wlds + swz(b0))         = s0; \
    *(uint4*)((char*)wlds + swz(b0+4096u))   = s1; \
    *(uint4*)((char*)wlds + swz(b0+8192u))   = s2; \
    *(uint4*)((char*)wlds + swz(b0+12288u))  = s3; \
    if (h>=1){ const uint4* ip=(const uint4*)(src + (nf + (size_t)(h-1)*128)*128); \
      _Pragma("unroll") \
      for (int j2=0;j2<8;j2++) \
        *(uint4*)((char*)inlds + swz((unsigned)(threadIdx.x+256*j2)*16)) = ip[threadIdx.x+256*j2]; } } \
  __syncthreads(); \
  _Pragma("unroll 1") \
  for (int ky=0; ky<3; ky++){ \
    int h2c = h+ky-1; \
    bool vld = (unsigned)h2c<128u; \
    _Pragma("unroll 1") \
    for (int kx=0; kx<3; kx++){ \
      int tap = ky*3+kx; \
      uint4 s0,s1,s2,s3; \
      if (tap<8){ const uint4* sp=(const uint4*)(wtap + (size_t)(tap+1)*16384 + chalf*8192); \
        s0=sp[threadIdx.x]; s1=sp[threadIdx.x+256]; s2=sp[threadIdx.x+512]; s3=sp[threadIdx.x+768]; } \
      uint4 tr[8]; \
      bool stg = (kx==2) && (ky<2) && (h+ky<128); \
      if (stg){ const uint4* ip=(const uint4*)(src + (nf + (size_t)(h+ky)*128)*128); \
        _Pragma("unroll") \
        for (int j2=0;j2<8;j2++) tr[j2]=ip[threadIdx.x+256*j2]; } \
      if (vld){ \
        int wA = wv*32 + mrow + kx - 1;            /* [-1,112] */ \
        int wAc = wA < 0 ? 0 : wA; \
        int wB = wA + 16;                          /* [15,128] */ \
        int wBc = wB > 127 ? 127 : wB; \
        bf16x8 aA[4], aB[4]; \
        _Pragma("unroll") \
        for (int kc=0;kc<4;kc++){ \
          aA[kc]=*(const bf16x8*)((const char*)inlds + swz((unsigned)(wAc*256 + kc*64 + quad*16))); \
          aB[kc]=*(const bf16x8*)((const char*)inlds + swz((unsigned)(wBc*256 + kc*64 + quad*16))); } \
        if (kx==0 && wv==0 && mrow==0){ _Pragma("unroll") for (int kc=0;kc<4;kc++) aA[kc]=(bf16x8){0,0,0,0,0,0,0,0}; } \
        if (kx==2 && wv==3 && mrow==15){ _Pragma("unroll") for (int kc=0;kc<4;kc++) aB[kc]=(bf16x8){0,0,0,0,0,0,0,0}; } \
        _Pragma("unroll") \
        for (int nt=0;nt<4;nt++){ \
          _Pragma("unroll") \
          for (int kc=0;kc<4;kc++){ \
            bf16x8 bfr=*(const bf16x8*)((const char*)wlds + swz((nt*16+mrow)*256 + kc*64 + quad*16)); \
            accA[nt]=__builtin_amdgcn_mfma_f32_16x16x32_bf16(aA[kc],bfr,accA[nt],0,0,0); \
            accB[nt]=__builtin_amdgcn_mfma_f32_16x16x32_bf16(aB[kc],bfr,accB[nt],0,0,0); \
          } \
        } \
      } \
      __syncthreads(); \
      if (tap<8){ unsigned b0=(unsigned)threadIdx.x*16; \
        *(uint4*)((char*)wlds + swz(b0))         = s0; \
        *(uint4*)((char*)wlds + swz(b0+4096u))   = s1; \
        *(uint4*)((char*)wlds + swz(b0+8192u))   = s2; \
        *(uint4*)((char*)wlds + swz(b0+12288u))  = s3; } \
      if (stg){ \
        _Pragma("unroll") \
        for (int j2=0;j2<8;j2++) \
          *(uint4*)((char*)inlds + swz((unsigned)(threadIdx.x+256*j2)*16)) = tr[j2]; } \
      if (tap<8) __syncthreads(); \
    } \
  }

// ---------- K6: 3x3 conv + bias + tanh-GELU, (N,C) bf16 out ----------
__global__ __launch_bounds__(256) void k_conv_gelu(const unsigned short* __restrict__ src,
                                                   const unsigned short* __restrict__ wtap,
                                                   const float* __restrict__ bias,
                                                   unsigned short* __restrict__ dst){
  CONV_PROLOG
  #pragma unroll
  for (int nt=0;nt<4;nt++){
    int col = chalf*64 + nt*16 + mrow;
    float bb = bias[col];
    #pragma unroll
    for (int r=0;r<4;r++){
      int pA = h*128 + wv*32 + quad*4 + r;
      float xA = accA[nt][r]+bb;
      float zA = 0.7978845608028654f*(xA+0.044715f*xA*xA*xA);
      dst[(nf+(size_t)pA)*128+col] = f2b(xA * __builtin_amdgcn_rcpf(1.f + __expf(-2.f*zA)));
      float xB = accB[nt][r]+bb;
      float zB = 0.7978845608028654f*(xB+0.044715f*xB*xB*xB);
      dst[(nf+(size_t)(pA+16))*128+col] = f2b(xB * __builtin_amdgcn_rcpf(1.f + __expf(-2.f*zB)));
    }
  }
}

// ---------- K7: 3x3 conv + bias + (vid1 + yb + r) -> d_out fp32 NCHW ----------
__global__ __launch_bounds__(256) void k_conv_final(const unsigned short* __restrict__ src,
                                                    const unsigned short* __restrict__ wtap,
                                                    const float* __restrict__ bias,
                                                    const unsigned short* __restrict__ yb,
                                                    const unsigned short* __restrict__ vid1,
                                                    float* __restrict__ out){
  CONV_PROLOG
  #pragma unroll
  for (int nt=0;nt<4;nt++){
    int col = chalf*64 + nt*16 + mrow;
    float bb = bias[col];
    #pragma unroll
    for (int r=0;r<4;r++){
      int pA = h*128 + wv*32 + quad*4 + r;
      size_t rowA = nf+(size_t)pA, rowB = rowA+16;
      float xA = accA[nt][r]+bb;
      out[(size_t)frame*2097152 + (size_t)col*16384 + pA] =
        b2f(vid1[rowA*128+col]) + b2f(yb[rowA*128+col]) + xA;
      float xB = accB[nt][r]+bb;
      out[(size_t)frame*2097152 + (size_t)col*16384 + pA + 16] =
        b2f(vid1[rowB*128+col]) + b2f(yb[rowB*128+col]) + xB;
    }
  }
}

extern "C" void kernel_launch(void* const* d_in, const int* in_sizes, int n_in,
                              void* d_out, int out_size, void* d_ws, size_t ws_size,
                              hipStream_t stream) {
  const float* vid  = (const float*)d_in[0];
  const float* flw  = (const float*)d_in[1];
  const float* g0   = (const float*)d_in[2];
  const float* b0   = (const float*)d_in[3];
  const float* Wq   = (const float*)d_in[4];
  const float* Wk   = (const float*)d_in[5];
  const float* Wv   = (const float*)d_in[6];
  const float* Wo   = (const float*)d_in[7];
  const float* g1   = (const float*)d_in[8];
  const float* b1   = (const float*)d_in[9];
  const float* wr1  = (const float*)d_in[10];
  const float* br1  = (const float*)d_in[11];
  const float* wr2  = (const float*)d_in[12];
  const float* br2  = (const float*)d_in[13];
  float* out = (float*)d_out;

  unsigned short* A  = (unsigned short*)d_ws;
  unsigned short* Bs = A + SLOT_ELEMS;
  unsigned short* Cs = Bs + SLOT_ELEMS;
  bool four = ws_size >= (size_t)4*SLOT_ELEMS*2 + 2*294912;
  unsigned short* D  = four ? (Cs + SLOT_ELEMS) : A;   // q/att/vid1 slot
  unsigned short* wt1 = Cs + SLOT_ELEMS + (four ? SLOT_ELEMS : 0);
  unsigned short* wt2 = wt1 + 147456;
  unsigned short* wm  = Cs + WM_OFF;   // bf16 proj mats in free upper half of Cs (v-fp8 uses lower 8MB)

  k_wprep   <<<832, 256, 0, stream>>>(wr1, wr2, Wq, Wk, Wv, Wo, wt1, wt2, wm);
  k_ln_nchw <<<256, 256, 0, stream>>>(vid, g0, b0, A);
  k_qkv     <<<512, 256, 0, stream>>>(A, wm, D, Bs, Cs);
  k_attn    <<<2048,256, 0, stream>>>(D, Bs, Cs, flw, D);
  k_wo      <<<256, 256, 0, stream>>>(D, wm, vid, g1, b1, D, Bs);   // fused LN: vid1->D, yb->Bs
  k_conv_gelu <<<1024,256,0, stream>>>(Bs, wt1, br1, Cs);
  k_conv_final<<<1024,256,0, stream>>>(Cs, wt2, br2, Bs, D, out);
}

// Round 12
// 414.496 us; speedup vs baseline: 1.1435x; 1.0354x over previous
//
#include <hip/hip_runtime.h>

// ---------- bf16 helpers (bit-level, RNE) ----------
__device__ __forceinline__ float bflo(unsigned int u){ return __builtin_bit_cast(float, (unsigned int)(u<<16)); }
__device__ __forceinline__ float bfhi(unsigned int u){ return __builtin_bit_cast(float, (unsigned int)(u & 0xffff0000u)); }
__device__ __forceinline__ float b2f(unsigned short s){ return __builtin_bit_cast(float, ((unsigned int)s)<<16); }
__device__ __forceinline__ unsigned short f2b(float f){
  unsigned int x = __builtin_bit_cast(unsigned int, f);
  x += 0x7fffu + ((x>>16)&1u);
  return (unsigned short)(x>>16);
}
__device__ __forceinline__ unsigned int packbf(float a, float b){
  return (unsigned int)f2b(a) | ((unsigned int)f2b(b)<<16);
}
__device__ __forceinline__ unsigned short f2h(float f){
  return __builtin_bit_cast(unsigned short, (_Float16)f);
}
__device__ __forceinline__ float dpp_swap1(float s){
  int so = __builtin_amdgcn_mov_dpp(__builtin_bit_cast(int, s), 0xB1, 0xF, 0xF, true); // quad_perm [1,0,3,2]
  return __builtin_bit_cast(float, so);
}
// LDS XOR swizzle: kills the 16-bank aliasing of 256B-stride row reads.
// Involution on byte addresses; applied to BOTH write and read sides.
__device__ __forceinline__ unsigned swz(unsigned b){ return b ^ (((b>>8)&7u)<<4); }

using bf16x8 = __attribute__((ext_vector_type(8))) short;
using f32x4  = __attribute__((ext_vector_type(4))) float;
using f32x2  = __attribute__((ext_vector_type(2))) float;
using h2     = __attribute__((ext_vector_type(2))) _Float16;

__device__ __forceinline__ h2 uh(unsigned int u){ return __builtin_bit_cast(h2, u); }

#define NPOS 65536          // T*H*W
#define SLOT_ELEMS 8388608  // NPOS*128 bf16 elements
#define WM_OFF 6291456      // wm offset (shorts) inside Cs slot (v-fp8 uses first 4194304)

// ---------- K0: conv weights fp32 (O,C,3,3) -> bf16 (tap,O,C);
// projection mats Wq(+scale),Wk,Wv,Wo fp32 -> bf16 [mat][o][c] ----
__global__ __launch_bounds__(256) void k_wprep(const float* __restrict__ w1,
                                               const float* __restrict__ w2,
                                               const float* __restrict__ Wq,
                                               const float* __restrict__ Wk,
                                               const float* __restrict__ Wv,
                                               const float* __restrict__ Wo,
                                               unsigned short* __restrict__ o1,
                                               unsigned short* __restrict__ o2,
                                               unsigned short* __restrict__ wm){
  int idx = blockIdx.x*256 + threadIdx.x;
  if (idx < 147456){
    int o = idx / 1152;
    int rem = idx - o*1152;
    int c = rem / 9;
    int tap = rem - c*9;
    int dsti = tap*16384 + o*128 + c;
    o1[dsti] = f2b(w1[idx]);
    o2[dsti] = f2b(w2[idx]);
  } else if (idx < 212992){
    int idx2 = idx - 147456;
    int mat = idx2 >> 14;
    int ij  = idx2 & 16383;
    // q scale = (1/sqrt(32)) * log2(e) folded into Wq
    float v = (mat==0) ? Wq[ij]*0.2550348613f
            : (mat==1) ? Wk[ij]
            : (mat==2) ? Wv[ij] : Wo[ij];
    wm[idx2] = f2b(v);
  }
}

// ---------- K2: FUSED LayerNorm + QKV projections. 128 rows/block, 512 blocks.
// Each lane loads its row's 32 channels straight from fp32 NCHW vid
// (16 same-quad lanes = full 64B segments), LN stats via 2-step shfl_xor
// across quads, normalized bf16 A-fragments kept in REGISTERS across all
// three matrices. Weights pre-converted bf16 (q pre-scaled), LDS XOR-swizzled.
// q,k -> fp16; v -> fp8 e4m3 ----
__global__ __launch_bounds__(256) void k_qkv(const float* __restrict__ vid,
                                             const float* __restrict__ g0,
                                             const float* __restrict__ b0,
                                             const unsigned short* __restrict__ wm,
                                             unsigned short* __restrict__ qf,
                                             unsigned short* __restrict__ kfo,
                                             unsigned short* __restrict__ vfo){
  __shared__ unsigned short wlds[16384];
  int wave = threadIdx.x>>6, lane = threadIdx.x&63;
  int m0w = blockIdx.x*128 + wave*32;
  int mrow = lane&15, quad = lane>>4;
  // ---- load + LayerNorm two rows (one per m-tile), keep bf16 frags in regs ----
  bf16x8 a[2][4];
  #pragma unroll
  for (int mt=0; mt<2; mt++){
    int nrow = m0w + mt*16 + mrow;
    int tt = nrow>>14, hww = nrow&16383;
    const float* base = vid + (size_t)tt*2097152 + hww;
    float v[32];
    float s=0.f, ss=0.f;
    #pragma unroll
    for (int kc=0;kc<4;kc++){
      #pragma unroll
      for (int j=0;j<8;j++){
        float x = base[(size_t)(quad*8+kc*32+j)*16384];
        v[kc*8+j]=x; s+=x; ss+=x*x;
      }
    }
    s += __shfl_xor(s,16,64); ss += __shfl_xor(ss,16,64);
    s += __shfl_xor(s,32,64); ss += __shfl_xor(ss,32,64);
    float mu  = s*0.0078125f;
    float var = fmaxf(ss*0.0078125f - mu*mu, 0.f);
    float rs  = rsqrtf(var + 1e-6f);
    #pragma unroll
    for (int kc=0;kc<4;kc++){
      bf16x8 t;
      #pragma unroll
      for (int j=0;j<8;j++){
        int ch = quad*8+kc*32+j;
        t[j] = (short)f2b((v[kc*8+j]-mu)*rs*g0[ch]+b0[ch]);
      }
      a[mt][kc] = t;
    }
  }
  #pragma unroll 1
  for (int mi=0; mi<3; mi++){
    int mat = 2-mi;                       // v, k, q
    __syncthreads();
    { const uint4* src=(const uint4*)(wm + mat*16384);
      #pragma unroll
      for (int i=0;i<8;i++){
        unsigned bb=(threadIdx.x+256*i)*16;
        *(uint4*)((char*)wlds + swz(bb)) = src[threadIdx.x+256*i];
      } }
    __syncthreads();
    #pragma unroll 1
    for (int mt=0; mt<2; mt++){
      int m0 = m0w + mt*16;
      for (int nt=0;nt<8;nt++){
        f32x4 acc = {0.f,0.f,0.f,0.f};
        #pragma unroll
        for (int kc=0;kc<4;kc++){
          bf16x8 bfr = *(const bf16x8*)((const char*)wlds + swz((nt*16+mrow)*256 + kc*64 + quad*16));
          acc = __builtin_amdgcn_mfma_f32_16x16x32_bf16(a[mt][kc], bfr, acc, 0,0,0);
        }
        int col = nt*16+mrow;
        if (mat==2){
          // v: fp8 e4m3, 128 bytes per pixel row
          unsigned char* op8 = (unsigned char*)vfo + (size_t)(m0 + quad*4)*128 + col;
          #pragma unroll
          for (int r=0;r<4;r++){
            int pk = __builtin_amdgcn_cvt_pk_fp8_f32(acc[r], acc[r], 0, false);
            op8[(size_t)r*128] = (unsigned char)(pk & 0xff);
          }
        } else {
          unsigned short* out = (mat==0) ? qf : kfo;
          unsigned short* op = out + (size_t)(m0 + quad*4)*128 + col;
          #pragma unroll
          for (int r=0;r<4;r++) op[(size_t)r*128] = f2h(acc[r]);   // fp16 (q scale in W)
        }
      }
    }
  }
}

// ---------- K3: attention (R5 verbatim — best measured 167 µs).
// 2 threads/pixel-head, 16 ch each; fdot2 QK; exp2f; fp8 V PV;
// cross-row prefetch pipeline. Output bf16 normal order ----
__global__ __launch_bounds__(256) void k_attn(const unsigned short* qf,
                                              const unsigned short* __restrict__ kf,
                                              const unsigned short* __restrict__ vf,
                                              const float* __restrict__ flw,
                                              unsigned short* attf){
  int xcd = blockIdx.x & 7;
  int j   = blockIdx.x >> 3;      // 0..255
  int t       = j >> 6;           // 0..3
  int r       = j & 63;
  int h_local = r >> 2;           // 0..15
  int wq      = r & 3;            // 0..3
  int h = xcd*16 + h_local;
  int w = wq*32 + (threadIdx.x >> 3);
  int head  = (threadIdx.x >> 1) & 3;
  int cpart = threadIdx.x & 1;
  int hw = (h<<7) + w;
  int n  = (t<<14) + hw;
  float fh = flw[t*32768 + hw];
  float fw = flw[t*32768 + 16384 + hw];
  unsigned coff = head*32 + cpart*16;     // this thread's 16-channel slice
  const unsigned char* vf8 = (const unsigned char*)vf;   // fp8 rows, 128B/pixel
  const uint4* qp = (const uint4*)(qf + (size_t)n*128 + coff);
  uint4 q0v = qp[0], q1v = qp[1];
  unsigned qw[8] = {q0v.x,q0v.y,q0v.z,q0v.w,q1v.x,q1v.y,q1v.z,q1v.w};
  float acc[16];
  #pragma unroll
  for (int i=0;i<16;i++) acc[i]=0.f;
  float l = 0.f;

  // ---- per-dt window params (x = dt+1), all precomputed ----
  int rowb0, rowb1, rowb2;     // clamped ti << 14
  int hb0, hb1, hb2;           // h + oh(dt)
  int wm30, wm31, wm32;        // w + ow(dt) - 3
  int w0c0, w0c1, w0c2;        // clamp(wm3)
  {
    int ti;
    ti = t-1; ti = ti<0?0:ti;   rowb0 = ti<<14;
    rowb1 = t<<14;
    ti = t+1; ti = ti>3?3:ti;   rowb2 = ti<<14;
    int oh = (int)rintf(fh*(-1.0f)), ow = (int)rintf(fw*(-1.0f));
    hb0 = h+oh; wm30 = w+ow-3;
    hb1 = h;    wm31 = w-3;
    oh = (int)rintf(fh*(1.0f)); ow = (int)rintf(fw*(1.0f));
    hb2 = h+oh; wm32 = w+ow-3;
    w0c0 = wm30<0?0:(wm30>127?127:wm30);
    w0c1 = wm31<0?0:(wm31>127?127:wm31);
    w0c2 = wm32<0?0:(wm32>127?127:wm32);
  }

  // ---- pipeline prologue: first position (dt=-1, dh=-3, tap 0) ----
  uint4 ka0, ka1, va;
  {
    int hi0 = hb0-3; hi0 = hi0<0?0:(hi0>127?127:hi0);
    unsigned b0 = ((unsigned)(rowb0 + (hi0<<7) + w0c0)<<7) + coff;
    ka0 = ((const uint4*)(kf + b0))[0];
    ka1 = ((const uint4*)(kf + b0))[1];
    va  = *(const uint4*)(vf8 + b0);
  }

  #pragma unroll
  for (int x=0; x<3; x++){
    const int rb_t = (x==0)?rowb0:((x==1)?rowb1:rowb2);
    const int hb   = (x==0)?hb0:((x==1)?hb1:hb2);
    const int wm3  = (x==0)?wm30:((x==1)?wm31:wm32);
    const int w0c  = (x==0)?w0c0:((x==1)?w0c1:w0c2);
    // next-dt first-row params (compile-time selected; unused for x==2)
    const int nrb  = (x==0)?rowb1:rowb2;
    const int nhb  = (x==0)?hb1:hb2;
    const int nw0c = (x==0)?w0c1:w0c2;
    #pragma unroll 1
    for (int dh=-3; dh<=3; dh++){
      int hi = hb+dh; hi = hi<0?0:(hi>127?127:hi);
      int rbase = rb_t + (hi<<7);
      #pragma unroll
      for (int i=0;i<7;i++){
        // ---- compute next prefetch address ----
        unsigned bon;
        if (i<6){
          int wi = wm3+i+1; wi = wi<0?0:(wi>127?127:wi);
          bon = ((unsigned)(rbase + wi)<<7) + coff;
        } else if (dh<3){
          // next row of same dt, tap 0
          int hi2 = hb+dh+1; hi2 = hi2<0?0:(hi2>127?127:hi2);
          bon = ((unsigned)(rb_t + (hi2<<7) + w0c)<<7) + coff;
        } else if (x<2){
          // first row of next dt, tap 0
          int hi2 = nhb-3; hi2 = hi2<0?0:(hi2>127?127:hi2);
          bon = ((unsigned)(nrb + (hi2<<7) + nw0c)<<7) + coff;
        } else {
          bon = coff;     // final iteration: harmless dummy
        }
        uint4 kb0 = ((const uint4*)(kf + bon))[0];
        uint4 kb1 = ((const uint4*)(kf + bon))[1];
        uint4 vb  = *(const uint4*)(vf8 + bon);
        // ---- QK: two dot2 chains of 4 (16 channels in 8 VALU ops) ----
        float s0 = 0.f, s1 = 0.f;
        s0 = __builtin_amdgcn_fdot2(uh(qw[0]), uh(ka0.x), s0, false);
        s0 = __builtin_amdgcn_fdot2(uh(qw[1]), uh(ka0.y), s0, false);
        s0 = __builtin_amdgcn_fdot2(uh(qw[2]), uh(ka0.z), s0, false);
        s0 = __builtin_amdgcn_fdot2(uh(qw[3]), uh(ka0.w), s0, false);
        s1 = __builtin_amdgcn_fdot2(uh(qw[4]), uh(ka1.x), s1, false);
        s1 = __builtin_amdgcn_fdot2(uh(qw[5]), uh(ka1.y), s1, false);
        s1 = __builtin_amdgcn_fdot2(uh(qw[6]), uh(ka1.z), s1, false);
        s1 = __builtin_amdgcn_fdot2(uh(qw[7]), uh(ka1.w), s1, false);
        float s = s0 + s1;
        s += dpp_swap1(s);               // combine the two channel halves
        float e = exp2f(s);              // 2^s == exp(scale*(q.k)), log2e folded in q
        l += e;
        // ---- PV: decode 16 fp8 -> f32 pairs, FMA with e ----
        f32x2 c0 = __builtin_amdgcn_cvt_pk_f32_fp8((int)va.x, false);
        f32x2 c1 = __builtin_amdgcn_cvt_pk_f32_fp8((int)va.x, true);
        f32x2 c2 = __builtin_amdgcn_cvt_pk_f32_fp8((int)va.y, false);
        f32x2 c3 = __builtin_amdgcn_cvt_pk_f32_fp8((int)va.y, true);
        f32x2 c4 = __builtin_amdgcn_cvt_pk_f32_fp8((int)va.z, false);
        f32x2 c5 = __builtin_amdgcn_cvt_pk_f32_fp8((int)va.z, true);
        f32x2 c6 = __builtin_amdgcn_cvt_pk_f32_fp8((int)va.w, false);
        f32x2 c7 = __builtin_amdgcn_cvt_pk_f32_fp8((int)va.w, true);
        acc[0]  += e*c0.x; acc[1]  += e*c0.y;
        acc[2]  += e*c1.x; acc[3]  += e*c1.y;
        acc[4]  += e*c2.x; acc[5]  += e*c2.y;
        acc[6]  += e*c3.x; acc[7]  += e*c3.y;
        acc[8]  += e*c4.x; acc[9]  += e*c4.y;
        acc[10] += e*c5.x; acc[11] += e*c5.y;
        acc[12] += e*c6.x; acc[13] += e*c6.y;
        acc[14] += e*c7.x; acc[15] += e*c7.y;
        ka0=kb0; ka1=kb1; va=vb;
      }
    }
  }
  float inv = 1.f/l;
  unsigned int* op = (unsigned int*)(attf + (size_t)n*128 + coff);
  #pragma unroll
  for (int i=0;i<8;i++) op[i]=packbf(acc[2*i]*inv, acc[2*i+1]*inv);
}

// ---------- K4: Wo projection + residual + FUSED LayerNorm epilogue.
// 256 rows/block, bf16 Wo from wm (LDS XOR-swizzled).
// Each output row is distributed across the 16 mrow-lanes of a quad
// (8 nt values/lane) -> 4-step shfl_xor gives row mean/var in-register.
// Writes vid1 = bf16(vid + attn@Wo) and yb = bf16(LN(vid1_f32)).
// vid1 may alias attf (a[] reads precede stores per m-tile) ----
__global__ __launch_bounds__(256) void k_wo(const unsigned short* attf,
                                            const unsigned short* __restrict__ wm,
                                            const float* __restrict__ vid,
                                            const float* __restrict__ g1,
                                            const float* __restrict__ b1,
                                            unsigned short* vid1,
                                            unsigned short* __restrict__ yb){
  __shared__ unsigned short wlds[16384];
  int wave = threadIdx.x>>6, lane = threadIdx.x&63;
  int m0w = blockIdx.x*256 + wave*64;
  int mrow = lane&15, quad = lane>>4;
  { const uint4* src=(const uint4*)(wm + 49152);
    #pragma unroll
    for (int i=0;i<8;i++){
      unsigned bb=(threadIdx.x+256*i)*16;
      *(uint4*)((char*)wlds + swz(bb)) = src[threadIdx.x+256*i];
    } }
  __syncthreads();
  #pragma unroll 1
  for (int mt=0; mt<4; mt++){
    int m0 = m0w + mt*16;
    bf16x8 a[4];
    const unsigned short* ap = attf + (size_t)(m0+mrow)*128 + quad*8;
    #pragma unroll
    for (int kc=0;kc<4;kc++) a[kc] = *(const bf16x8*)(ap + kc*32);
    f32x4 acc8[8];
    #pragma unroll
    for (int nt=0;nt<8;nt++){
      f32x4 acc={0.f,0.f,0.f,0.f};
      #pragma unroll
      for (int kc=0;kc<4;kc++){
        bf16x8 bfr = *(const bf16x8*)((const char*)wlds + swz((nt*16+mrow)*256 + kc*64 + quad*16));
        acc = __builtin_amdgcn_mfma_f32_16x16x32_bf16(a[kc], bfr, acc, 0,0,0);
      }
      acc8[nt]=acc;
    }
    #pragma unroll
    for (int r=0;r<4;r++){
      int nrow = m0 + quad*4 + r;
      int tt = nrow>>14, hww = nrow&16383;
      float v0,v1,v2,v3,v4,v5,v6,v7;
      float s=0.f, ss=0.f;
      v0 = vid[(size_t)tt*2097152 + (size_t)(0*16+mrow)*16384 + hww] + acc8[0][r];
      v1 = vid[(size_t)tt*2097152 + (size_t)(1*16+mrow)*16384 + hww] + acc8[1][r];
      v2 = vid[(size_t)tt*2097152 + (size_t)(2*16+mrow)*16384 + hww] + acc8[2][r];
      v3 = vid[(size_t)tt*2097152 + (size_t)(3*16+mrow)*16384 + hww] + acc8[3][r];
      v4 = vid[(size_t)tt*2097152 + (size_t)(4*16+mrow)*16384 + hww] + acc8[4][r];
      v5 = vid[(size_t)tt*2097152 + (size_t)(5*16+mrow)*16384 + hww] + acc8[5][r];
      v6 = vid[(size_t)tt*2097152 + (size_t)(6*16+mrow)*16384 + hww] + acc8[6][r];
      v7 = vid[(size_t)tt*2097152 + (size_t)(7*16+mrow)*16384 + hww] + acc8[7][r];
      s  = ((v0+v1)+(v2+v3)) + ((v4+v5)+(v6+v7));
      ss = ((v0*v0+v1*v1)+(v2*v2+v3*v3)) + ((v4*v4+v5*v5)+(v6*v6+v7*v7));
      #pragma unroll
      for (int m=1;m<16;m<<=1){ s += __shfl_xor(s,m,64); ss += __shfl_xor(ss,m,64); }
      float mu  = s*0.0078125f;
      float var = fmaxf(ss*0.0078125f - mu*mu, 0.f);
      float rs  = rsqrtf(var + 1e-6f);
      float vv[8] = {v0,v1,v2,v3,v4,v5,v6,v7};
      #pragma unroll
      for (int nt=0;nt<8;nt++){
        int col = nt*16+mrow;
        vid1[(size_t)nrow*128 + col] = f2b(vv[nt]);
        yb[(size_t)nrow*128 + col]   = f2b((vv[nt]-mu)*rs*g1[col] + b1[col]);
      }
    }
  }
}

// ---------- K6/K7 shared conv core: chalf-split + LDS-staged input rows
// + XCD-chunk block swizzle (h-neighbors & chalf-pairs share an XCD L2).
// Block = (frame, row h, col-half). M=128 (full row), 64 out channels.
// Input row (32KB) staged in inlds once per ky, read by all 3 kx taps via
// swizzled ds_read_b128; next row register-prefetched during kx==2 compute.
// Weights: 16KB wlds, reg-prefetch next tap. 48KB LDS total.
#define CONV_PROLOG \
  __shared__ unsigned short wlds[8192]; \
  __shared__ unsigned short inlds[16384]; \
  int wv = threadIdx.x>>6, lane = threadIdx.x&63; \
  int mrow = lane&15, quad = lane>>4; \
  int wg = (int)((blockIdx.x&7)*128 + (blockIdx.x>>3));   /* XCD chunk swizzle, 1024%8==0 */ \
  int chalf = wg & 1; \
  int h = (wg>>1) & 127; \
  int frame = wg>>8; \
  size_t nf = (size_t)frame*16384; \
  f32x4 accA[4], accB[4]; \
  _Pragma("unroll") \
  for (int i=0;i<4;i++){ accA[i]=(f32x4){0.f,0.f,0.f,0.f}; accB[i]=(f32x4){0.f,0.f,0.f,0.f}; } \
  { const uint4* sp=(const uint4*)(wtap + chalf*8192); \
    uint4 s0=sp[threadIdx.x], s1=sp[threadIdx.x+256], s2=sp[threadIdx.x+512], s3=sp[threadIdx.x+768]; \
    unsigned b0=(unsigned)threadIdx.x*16; \
    *(uint4*)((char*)wlds + swz(b0))         = s0; \
    *(uint4*)((char*)wlds + swz(b0+4096u))   = s1; \
    *(uint4*)((char*)wlds + swz(b0+8192u))   = s2; \
    *(uint4*)((char*)wlds + swz(b0+12288u))  = s3; \
    if (h>=1){ const uint4* ip=(const uint4*)(src + (nf + (size_t)(h-1)*128)*128); \
      _Pragma("unroll") \
      for (int j2=0;j2<8;j2++) \
        *(uint4*)((char*)inlds + swz((unsigned)(threadIdx.x+256*j2)*16)) = ip[threadIdx.x+256*j2]; } } \
  __syncthreads(); \
  _Pragma("unroll 1") \
  for (int ky=0; ky<3; ky++){ \
    int h2c = h+ky-1; \
    bool vld = (unsigned)h2c<128u; \
    _Pragma("unroll 1") \
    for (int kx=0; kx<3; kx++){ \
      int tap = ky*3+kx; \
      uint4 s0,s1,s2,s3; \
      if (tap<8){ const uint4* sp=(const uint4*)(wtap + (size_t)(tap+1)*16384 + chalf*8192); \
        s0=sp[threadIdx.x]; s1=sp[threadIdx.x+256]; s2=sp[threadIdx.x+512]; s3=sp[threadIdx.x+768]; } \
      uint4 tr[8]; \
      bool stg = (kx==2) && (ky<2) && (h+ky<128); \
      if (stg){ const uint4* ip=(const uint4*)(src + (nf + (size_t)(h+ky)*128)*128); \
        _Pragma("unroll") \
        for (int j2=0;j2<8;j2++) tr[j2]=ip[threadIdx.x+256*j2]; } \
      if (vld){ \
        int wA = wv*32 + mrow + kx - 1;            /* [-1,112] */ \
        int wAc = wA < 0 ? 0 : wA; \
        int wB = wA + 16;                          /* [15,128] */ \
        int wBc = wB > 127 ? 127 : wB; \
        bf16x8 aA[4], aB[4]; \
        _Pragma("unroll") \
        for (int kc=0;kc<4;kc++){ \
          aA[kc]=*(const bf16x8*)((const char*)inlds + swz((unsigned)(wAc*256 + kc*64 + quad*16))); \
          aB[kc]=*(const bf16x8*)((const char*)inlds + swz((unsigned)(wBc*256 + kc*64 + quad*16))); } \
        if (kx==0 && wv==0 && mrow==0){ _Pragma("unroll") for (int kc=0;kc<4;kc++) aA[kc]=(bf16x8){0,0,0,0,0,0,0,0}; } \
        if (kx==2 && wv==3 && mrow==15){ _Pragma("unroll") for (int kc=0;kc<4;kc++) aB[kc]=(bf16x8){0,0,0,0,0,0,0,0}; } \
        _Pragma("unroll") \
        for (int nt=0;nt<4;nt++){ \
          _Pragma("unroll") \
          for (int kc=0;kc<4;kc++){ \
            bf16x8 bfr=*(const bf16x8*)((const char*)wlds + swz((nt*16+mrow)*256 + kc*64 + quad*16)); \
            accA[nt]=__builtin_amdgcn_mfma_f32_16x16x32_bf16(aA[kc],bfr,accA[nt],0,0,0); \
            accB[nt]=__builtin_amdgcn_mfma_f32_16x16x32_bf16(aB[kc],bfr,accB[nt],0,0,0); \
          } \
        } \
      } \
      __syncthreads(); \
      if (tap<8){ unsigned b0=(unsigned)threadIdx.x*16; \
        *(uint4*)((char*)wlds + swz(b0))         = s0; \
        *(uint4*)((char*)wlds + swz(b0+4096u))   = s1; \
        *(uint4*)((char*)wlds + swz(b0+8192u))   = s2; \
        *(uint4*)((char*)wlds + swz(b0+12288u))  = s3; } \
      if (stg){ \
        _Pragma("unroll") \
        for (int j2=0;j2<8;j2++) \
          *(uint4*)((char*)inlds + swz((unsigned)(threadIdx.x+256*j2)*16)) = tr[j2]; } \
      if (tap<8) __syncthreads(); \
    } \
  }

// ---------- K6: 3x3 conv + bias + tanh-GELU, (N,C) bf16 out ----------
__global__ __launch_bounds__(256) void k_conv_gelu(const unsigned short* __restrict__ src,
                                                   const unsigned short* __restrict__ wtap,
                                                   const float* __restrict__ bias,
                                                   unsigned short* __restrict__ dst){
  CONV_PROLOG
  #pragma unroll
  for (int nt=0;nt<4;nt++){
    int col = chalf*64 + nt*16 + mrow;
    float bb = bias[col];
    #pragma unroll
    for (int r=0;r<4;r++){
      int pA = h*128 + wv*32 + quad*4 + r;
      float xA = accA[nt][r]+bb;
      float zA = 0.7978845608028654f*(xA+0.044715f*xA*xA*xA);
      dst[(nf+(size_t)pA)*128+col] = f2b(xA * __builtin_amdgcn_rcpf(1.f + __expf(-2.f*zA)));
      float xB = accB[nt][r]+bb;
      float zB = 0.7978845608028654f*(xB+0.044715f*xB*xB*xB);
      dst[(nf+(size_t)(pA+16))*128+col] = f2b(xB * __builtin_amdgcn_rcpf(1.f + __expf(-2.f*zB)));
    }
  }
}

// ---------- K7: 3x3 conv + bias + (vid1 + yb + r) -> d_out fp32 NCHW ----------
__global__ __launch_bounds__(256) void k_conv_final(const unsigned short* __restrict__ src,
                                                    const unsigned short* __restrict__ wtap,
                                                    const float* __restrict__ bias,
                                                    const unsigned short* __restrict__ yb,
                                                    const unsigned short* __restrict__ vid1,
                                                    float* __restrict__ out){
  CONV_PROLOG
  #pragma unroll
  for (int nt=0;nt<4;nt++){
    int col = chalf*64 + nt*16 + mrow;
    float bb = bias[col];
    #pragma unroll
    for (int r=0;r<4;r++){
      int pA = h*128 + wv*32 + quad*4 + r;
      size_t rowA = nf+(size_t)pA, rowB = rowA+16;
      float xA = accA[nt][r]+bb;
      out[(size_t)frame*2097152 + (size_t)col*16384 + pA] =
        b2f(vid1[rowA*128+col]) + b2f(yb[rowA*128+col]) + xA;
      float xB = accB[nt][r]+bb;
      out[(size_t)frame*2097152 + (size_t)col*16384 + pA + 16] =
        b2f(vid1[rowB*128+col]) + b2f(yb[rowB*128+col]) + xB;
    }
  }
}

extern "C" void kernel_launch(void* const* d_in, const int* in_sizes, int n_in,
                              void* d_out, int out_size, void* d_ws, size_t ws_size,
                              hipStream_t stream) {
  const float* vid  = (const float*)d_in[0];
  const float* flw  = (const float*)d_in[1];
  const float* g0   = (const float*)d_in[2];
  const float* b0   = (const float*)d_in[3];
  const float* Wq   = (const float*)d_in[4];
  const float* Wk   = (const float*)d_in[5];
  const float* Wv   = (const float*)d_in[6];
  const float* Wo   = (const float*)d_in[7];
  const float* g1   = (const float*)d_in[8];
  const float* b1   = (const float*)d_in[9];
  const float* wr1  = (const float*)d_in[10];
  const float* br1  = (const float*)d_in[11];
  const float* wr2  = (const float*)d_in[12];
  const float* br2  = (const float*)d_in[13];
  float* out = (float*)d_out;

  unsigned short* A  = (unsigned short*)d_ws;
  unsigned short* Bs = A + SLOT_ELEMS;
  unsigned short* Cs = Bs + SLOT_ELEMS;
  bool four = ws_size >= (size_t)4*SLOT_ELEMS*2 + 2*294912;
  unsigned short* D  = four ? (Cs + SLOT_ELEMS) : A;   // q/att/vid1 slot
  unsigned short* wt1 = Cs + SLOT_ELEMS + (four ? SLOT_ELEMS : 0);
  unsigned short* wt2 = wt1 + 147456;
  unsigned short* wm  = Cs + WM_OFF;   // bf16 proj mats in free upper half of Cs (v-fp8 uses lower 8MB)

  k_wprep   <<<832, 256, 0, stream>>>(wr1, wr2, Wq, Wk, Wv, Wo, wt1, wt2, wm);
  k_qkv     <<<512, 256, 0, stream>>>(vid, g0, b0, wm, D, Bs, Cs);
  k_attn    <<<2048,256, 0, stream>>>(D, Bs, Cs, flw, D);
  k_wo      <<<256, 256, 0, stream>>>(D, wm, vid, g1, b1, D, Bs);   // fused LN: vid1->D, yb->Bs
  k_conv_gelu <<<1024,256,0, stream>>>(Bs, wt1, br1, Cs);
  k_conv_final<<<1024,256,0, stream>>>(Cs, wt2, br2, Bs, D, out);
}